// Round 4
// baseline (612.238 us; speedup 1.0000x reference)
//
#include <hip/hip_runtime.h>
#include <cstdint>
#include <cstddef>

// ---------------------------------------------------------------------------
// Problem constants: B=2, C=128, D=H=W=32, nh=8, hd=16, L=32
// Tokens: t = b*32768 + d*1024 + h*32 + w   (65536 tokens, 128 channels)
// ---------------------------------------------------------------------------

#define NTOK 65536
#define SPAT 32768

// ws offsets (floats). Timeline reuse:
//   R0    : lf (conv out, fp32) -> attention accum (fp32)
//   MPRE  : m_pre fp32 ; XTOK : token-major x fp32 ; INT : bf16 pos_emb -> bf16 x_mod
//   QKVB  : bf16 qkv [t][384], overlays dead MPRE+XTOK
#define WS_R0     0ull          // 8388608
#define WS_MPRE   8388608ull    // 8388608
#define WS_XTOK   16777216ull   // 8388608
#define WS_INT    25165824ull   // 4194304 floats (8388608 ush): pos_emb bf16 -> x_mod bf16
#define WS_QKVB   8388608ull    // 12582912 floats (25165824 ush)
#define WS_CONVP  33554432ull   // 221184 (442368 ush) conv weights bf16
#define WS_QKVP   33775616ull   // 24576  (49152 ush)  qkv_w bf16 [o][i]
#define WS_WCP    33800192ull   // 8192   (16384 ush)  (mod_w1@lp_w2) bf16 [o][i]
#define WS_MODW2P 33808384ull   // 8192
#define WS_PROJP  33816576ull   // 8192
#define WS_BC     33824768ull   // 128    combined bias
#define WS_RBUF   33824896ull   // 432    [axial][head][18]
#define WS_PS     33825328ull   // 65536  per-block partial sums (512 blocks x 128)
#define WS_PSS    33890864ull   // 65536
#define WS_MU1    33956400ull   // 256
#define WS_RS1    33956656ull   // 256
#define WS_MU2    33956912ull   // 256
#define WS_RS2    33957168ull   // 256
// total 33957424 floats = 135.8 MB

typedef __attribute__((ext_vector_type(8))) short short8;
typedef __attribute__((ext_vector_type(4))) float f32x4;

__device__ __forceinline__ float gelu_f(float x) {
  return 0.5f * x * (1.0f + erff(x * 0.70710678118654752f));
}
__device__ __forceinline__ float sigmoid_f(float x) {
  return 1.0f / (1.0f + expf(-x));
}
__device__ __forceinline__ unsigned short f2bf(float x) {  // RNE f32->bf16
  unsigned int u = __float_as_uint(x);
  unsigned int r = u + 0x7fffu + ((u >> 16) & 1u);
  return (unsigned short)(r >> 16);
}
__device__ __forceinline__ short8 pack_bf8(float4 v0, float4 v1) {
  short8 r;
  r[0] = (short)f2bf(v0.x); r[1] = (short)f2bf(v0.y);
  r[2] = (short)f2bf(v0.z); r[3] = (short)f2bf(v0.w);
  r[4] = (short)f2bf(v1.x); r[5] = (short)f2bf(v1.y);
  r[6] = (short)f2bf(v1.z); r[7] = (short)f2bf(v1.w);
  return r;
}
// 16 consecutive bf16 -> 16 fp32
__device__ __forceinline__ void bf16x16_load(const unsigned short* p, float* f) {
  const uint4 a = *(const uint4*)p;
  const uint4 b = *(const uint4*)(p + 8);
  const unsigned int w[8] = {a.x, a.y, a.z, a.w, b.x, b.y, b.z, b.w};
  #pragma unroll
  for (int i = 0; i < 8; ++i) {
    f[2 * i] = __uint_as_float(w[i] << 16);
    f[2 * i + 1] = __uint_as_float(w[i] & 0xffff0000u);
  }
}
__device__ __forceinline__ float dot3(const float* a, const float* b) {
  return a[0] * b[0] + a[1] * b[1] + a[2] * b[2];
}
__device__ __forceinline__ void cross3(const float* a, const float* b, float* c) {
  c[0] = a[1] * b[2] - a[2] * b[1];
  c[1] = a[2] * b[0] - a[0] * b[2];
  c[2] = a[0] * b[1] - a[1] * b[0];
}

// exact port of _r6_to_matrix for one head (6 floats in, 9 out row-major)
__device__ void r6_to_matrix(const float* r6, float* R) {
  float v1[3] = {r6[0], r6[1], r6[2]};
  float n1 = sqrtf(dot3(v1, v1));
  float inv1 = 1.0f / (n1 + 1e-7f);
  v1[0] *= inv1; v1[1] *= inv1; v1[2] *= inv1;
  float v2[3] = {r6[3], r6[4], r6[5]};
  float d = dot3(v2, v1);
  v2[0] -= d * v1[0]; v2[1] -= d * v1[1]; v2[2] -= d * v1[2];
  float n2 = sqrtf(dot3(v2, v2));
  float inv2 = 1.0f / (n2 + 1e-7f);
  v2[0] *= inv2; v2[1] *= inv2; v2[2] *= inv2;
  float v3[3]; cross3(v1, v2, v3);
  float cx[3]; cross3(v2, v3, cx);
  float det = dot3(v1, cx);
  if (det < 0.0f) { v3[0] = -v3[0]; v3[1] = -v3[1]; v3[2] = -v3[2]; }
  R[0] = v1[0]; R[1] = v1[1]; R[2] = v1[2];
  R[3] = v2[0]; R[4] = v2[1]; R[5] = v2[2];
  R[6] = v3[0]; R[7] = v3[1]; R[8] = v3[2];
}

// exact port of _ensure_matrix for one head (9 in row-major, 9 out)
__device__ void ensure_matrix(const float* Rin, float* Ro) {
  float a[3] = {Rin[0] + 1e-6f, Rin[1] + 1e-6f, Rin[2] + 1e-6f};
  float na = fmaxf(sqrtf(dot3(a, a)), 1e-12f);
  float v1[3] = {a[0] / na, a[1] / na, a[2] / na};
  float b0[3] = {Rin[3], Rin[4], Rin[5]};
  float d = dot3(b0, v1);
  float bb[3] = {b0[0] - d * v1[0] + 1e-6f, b0[1] - d * v1[1] + 1e-6f, b0[2] - d * v1[2] + 1e-6f};
  float nb = fmaxf(sqrtf(dot3(bb, bb)), 1e-12f);
  float v2[3] = {bb[0] / nb, bb[1] / nb, bb[2] / nb};
  float v3[3]; cross3(v1, v2, v3);
  float cx[3]; cross3(v2, v3, cx);
  float det = dot3(v1, cx);
  if (det < 0.0f) { v3[0] = -v3[0]; v3[1] = -v3[1]; v3[2] = -v3[2]; }
  float Rn[9] = {v1[0], v1[1], v1[2], v2[0], v2[1], v2[2], v3[0], v3[1], v3[2]};
  float T1[9], T2[9];
  for (int i = 0; i < 3; ++i)
    for (int j = 0; j < 3; ++j) {
      float s = 0.f;
      for (int k = 0; k < 3; ++k) s += Rn[k * 3 + i] * Rn[k * 3 + j];
      T1[i * 3 + j] = s;
    }
  for (int i = 0; i < 3; ++i)
    for (int j = 0; j < 3; ++j) {
      float s = 0.f;
      for (int k = 0; k < 3; ++k) s += T1[i * 3 + k] * Rn[j * 3 + k];
      T2[i * 3 + j] = s;
    }
  for (int i = 0; i < 9; ++i) Ro[i] = 0.5f * (Rn[i] + T2[i]);
}

// ---------------------------------------------------------------------------
// K0: rotation matrices for 3 axials x 8 heads
// ---------------------------------------------------------------------------
__global__ void prep_r_kernel(const float* __restrict__ Ad, const float* __restrict__ Ah,
                              const float* __restrict__ Aw, const float* __restrict__ Rd,
                              const float* __restrict__ Rh, const float* __restrict__ Rw,
                              float* __restrict__ Rbuf) {
  int tid = threadIdx.x;
  if (tid >= 24) return;
  int ax = tid >> 3, h = tid & 7;
  const float* A = (ax == 0) ? Ad : ((ax == 1) ? Ah : Aw);
  const float* R = (ax == 0) ? Rd : ((ax == 1) ? Rh : Rw);
  float Rq[9], Rv[9];
  r6_to_matrix(A + h * 6, Rq);
  ensure_matrix(R + h * 9, Rv);
  float* dst = Rbuf + (ax * 8 + h) * 18;
  for (int i = 0; i < 9; ++i) { dst[i] = Rq[i]; dst[9 + i] = Rv[i]; }
}

// ---------------------------------------------------------------------------
// K0b: bf16 weight packs + fused (mod_w1 @ lp_w2) matrix
// ---------------------------------------------------------------------------
__global__ __launch_bounds__(256) void prep_w_kernel(
    const float* __restrict__ lp_w1, const float* __restrict__ qkv_w,
    const float* __restrict__ mod_w1, const float* __restrict__ lp_w2,
    const float* __restrict__ lp_b2, const float* __restrict__ mod_b1,
    const float* __restrict__ mod_w2, const float* __restrict__ proj_w,
    unsigned short* __restrict__ convP, unsigned short* __restrict__ qkvP,
    unsigned short* __restrict__ WcP, unsigned short* __restrict__ modw2P,
    unsigned short* __restrict__ projP, float* __restrict__ bc) {
  int gid = blockIdx.x * 256 + threadIdx.x;  // 65536 threads
  for (int f = gid; f < 442368; f += 65536) {
    int ci = f & 127;
    int rr = f >> 7;        // (tap*128+co)*3 + dx
    int dx = rr % 3;
    int r2 = rr / 3;
    int co = r2 & 127;
    int tap = r2 >> 7;
    int dz = tap / 3, dy = tap % 3;
    convP[f] = f2bf(lp_w1[(co * 128 + ci) * 27 + dz * 9 + dy * 3 + dx]);
  }
  if (gid < 49152) qkvP[gid] = f2bf(qkv_w[gid]);
  if (gid < 16384) {
    modw2P[gid] = f2bf(mod_w2[gid]);
    projP[gid] = f2bf(proj_w[gid]);
    int o = gid >> 7, i = gid & 127;
    float s = 0.f;
    for (int c = 0; c < 128; ++c) s += mod_w1[o * 128 + c] * lp_w2[c * 128 + i];
    WcP[gid] = f2bf(s);
  }
  if (gid < 128) {
    float s = 0.f;
    for (int c = 0; c < 128; ++c) s += mod_w1[gid * 128 + c] * lp_b2[c];
    bc[gid] = s + mod_b1[gid];
  }
}

// ---------------------------------------------------------------------------
// K0c: merged transposes. Per (b,d,h) plane: x -> xtok fp32, pos_emb -> inT bf16
// ---------------------------------------------------------------------------
__global__ __launch_bounds__(256) void transpose_kernel(const float* __restrict__ x,
                                                        const float* __restrict__ pe,
                                                        float* __restrict__ xtok,
                                                        unsigned short* __restrict__ inT) {
  __shared__ float lds[32][132];
  int blk = blockIdx.x;  // b*1024 + d*32 + h
  int b = blk >> 10;
  int dh = blk & 1023;
  int tid = threadIdx.x;
  size_t planebase = ((size_t)b << 22) + ((size_t)dh << 5);
  size_t tb = ((size_t)blk) << 5;
  #pragma unroll
  for (int r = 0; r < 16; ++r) {
    int idx = r * 256 + tid;
    int ci = idx >> 5, w = idx & 31;
    lds[w][ci] = x[planebase + ((size_t)ci << 15) + w];
  }
  __syncthreads();
  #pragma unroll
  for (int r = 0; r < 16; ++r) {
    int idx = r * 256 + tid;
    int w = idx >> 7, ci = idx & 127;
    xtok[(tb + w) * 128 + ci] = lds[w][ci];
  }
  __syncthreads();
  #pragma unroll
  for (int r = 0; r < 16; ++r) {
    int idx = r * 256 + tid;
    int ci = idx >> 5, w = idx & 31;
    lds[w][ci] = pe[planebase + ((size_t)ci << 15) + w];
  }
  __syncthreads();
  #pragma unroll
  for (int r = 0; r < 16; ++r) {
    int idx = r * 256 + tid;
    int w = idx >> 7, ci = idx & 127;
    inT[(tb + w) * 128 + ci] = f2bf(lds[w][ci]);
  }
}

// ---------------------------------------------------------------------------
// K1: 3x3x3 circular conv via bf16 MFMA, v2.
// Block: 128 tokens (4 h-rows x 32 w) x 128 co; 8 waves 2x4 (64tok x 32co each).
// Per-dz staging of 6-row halo (dy = LDS row offset); T14 reg-prefetch of next dz.
// Fused instance-norm partial stats in epilogue.
// ---------------------------------------------------------------------------
__global__ __launch_bounds__(512, 4) void conv_mfma_kernel(
    const unsigned short* __restrict__ inT, const unsigned short* __restrict__ Bp,
    const float* __restrict__ b1, float* __restrict__ out,
    float* __restrict__ ps, float* __restrict__ pss) {
  __shared__ unsigned short Als[24576];  // 48KB: 192 tok-slots (6 rows x 32 w) x 128 ci
  __shared__ float sumb[128][2];
  __shared__ float sqb[128][2];
  const int blk = blockIdx.x;
  const int b = blk >> 8, d = (blk >> 3) & 31, hg = blk & 7;
  const int h0 = hg << 2;
  const int tid = threadIdx.x;
  const int lane = tid & 63, wid = tid >> 6;
  const int wm = wid >> 2, wn = wid & 3;
  const int l15 = lane & 15, l4 = lane >> 4;

  f32x4 acc[4][2];
  #pragma unroll
  for (int mt = 0; mt < 4; ++mt)
    #pragma unroll
    for (int nt = 0; nt < 2; ++nt)
      #pragma unroll
      for (int r = 0; r < 4; ++r) acc[mt][nt][r] = 0.f;

  int mw[4], mhh[4];
  #pragma unroll
  for (int mt = 0; mt < 4; ++mt) {
    int m = wm * 64 + mt * 16 + l15;
    mhh[mt] = m >> 5;
    mw[mt] = m & 31;
  }
  const size_t tokbase = ((size_t)b << 15) + ((size_t)d << 10) + ((size_t)h0 << 5);

  uint4 pf[6];
  // issue + commit dz=0 stage (rows h0-1 .. h0+4 of plane (d-1))
  {
    const int zr = (d + 31) & 31;
    #pragma unroll
    for (int p = 0; p < 6; ++p) {
      const int g = p * 512 + tid;
      const int tok = g >> 4, gi = g & 15;
      const int r = tok >> 5, w = tok & 31;
      const int yr = (h0 + r + 31) & 31;
      const size_t srcbyte = ((((size_t)b << 15) + ((size_t)zr << 10) + ((size_t)yr << 5) + w) << 8)
                             + (size_t)((gi ^ (w & 7)) << 4);
      pf[p] = *(const uint4*)((const char*)inT + srcbyte);
    }
  }
  #pragma unroll
  for (int p = 0; p < 6; ++p) {
    const int g = p * 512 + tid;
    *(uint4*)((char*)Als + g * 16) = pf[p];
  }
  __syncthreads();

  for (int dz = 0; dz < 3; ++dz) {
    if (dz < 2) {  // T14: issue next-dz loads now; commit after compute+barrier
      const int zr = (d + dz) & 31;
      #pragma unroll
      for (int p = 0; p < 6; ++p) {
        const int g = p * 512 + tid;
        const int tok = g >> 4, gi = g & 15;
        const int r = tok >> 5, w = tok & 31;
        const int yr = (h0 + r + 31) & 31;
        const size_t srcbyte = ((((size_t)b << 15) + ((size_t)zr << 10) + ((size_t)yr << 5) + w) << 8)
                               + (size_t)((gi ^ (w & 7)) << 4);
        pf[p] = *(const uint4*)((const char*)inT + srcbyte);
      }
    }
    #pragma unroll
    for (int dy = 0; dy < 3; ++dy) {
      const int tap = dz * 3 + dy;
      int brow[2];
      #pragma unroll
      for (int nt = 0; nt < 2; ++nt) {
        const int co = wn * 32 + nt * 16 + l15;
        brow[nt] = (tap * 128 + co) * 384;
      }
      #pragma unroll
      for (int dx = 0; dx < 3; ++dx) {
        int abase[4], asw[4];
        #pragma unroll
        for (int mt = 0; mt < 4; ++mt) {
          const int wsft = (mw[mt] + dx + 31) & 31;
          const int stok = (mhh[mt] + dy) * 32 + wsft;
          abase[mt] = stok * 256;
          asw[mt] = (wsft & 7) << 4;
        }
        #pragma unroll
        for (int ks = 0; ks < 4; ++ks) {
          const int k2 = (ks * 32 + l4 * 8) * 2;
          const int koff = dx * 128 + ks * 32 + l4 * 8;
          short8 afr[4], bfr[2];
          #pragma unroll
          for (int mt = 0; mt < 4; ++mt)
            afr[mt] = *(const short8*)((const char*)Als + abase[mt] + (k2 ^ asw[mt]));
          #pragma unroll
          for (int nt = 0; nt < 2; ++nt)
            bfr[nt] = *(const short8*)(Bp + brow[nt] + koff);
          #pragma unroll
          for (int mt = 0; mt < 4; ++mt)
            #pragma unroll
            for (int nt = 0; nt < 2; ++nt)
              acc[mt][nt] = __builtin_amdgcn_mfma_f32_16x16x32_bf16(afr[mt], bfr[nt],
                                                                    acc[mt][nt], 0, 0, 0);
        }
      }
    }
    if (dz < 2) {
      __syncthreads();  // all waves done reading current Als
      #pragma unroll
      for (int p = 0; p < 6; ++p) {
        const int g = p * 512 + tid;
        *(uint4*)((char*)Als + g * 16) = pf[p];
      }
      __syncthreads();
    }
  }

  // epilogue: bias + store + fused stats partials
  #pragma unroll
  for (int nt = 0; nt < 2; ++nt) {
    const int co = wn * 32 + nt * 16 + l15;
    const float bias = b1[co];
    float s = 0.f, q = 0.f;
    #pragma unroll
    for (int mt = 0; mt < 4; ++mt) {
      #pragma unroll
      for (int r = 0; r < 4; ++r) {
        const int m = wm * 64 + mt * 16 + l4 * 4 + r;
        const float v = acc[mt][nt][r] + bias;
        out[(tokbase + m) * 128 + co] = v;
        s += v; q += v * v;
      }
    }
    s += __shfl_xor(s, 16); s += __shfl_xor(s, 32);
    q += __shfl_xor(q, 16); q += __shfl_xor(q, 32);
    if (l4 == 0) { sumb[co][wm] = s; sqb[co][wm] = q; }
  }
  __syncthreads();
  if (tid < 128) {
    ps[blk * 128 + tid] = sumb[tid][0] + sumb[tid][1];
    pss[blk * 128 + tid] = sqb[tid][0] + sqb[tid][1];
  }
}

// ---------------------------------------------------------------------------
// K2: stats finalize (512 partial blocks, 256 per batch)
// ---------------------------------------------------------------------------
__global__ void stats_final_kernel(const float* __restrict__ ps, const float* __restrict__ pss,
                                   float* __restrict__ mu, float* __restrict__ rs) {
  int tid = threadIdx.x;  // tid = b*128 + c
  int b = tid >> 7, c = tid & 127;
  float s = 0.f, ss = 0.f;
  for (int blk = b * 256; blk < b * 256 + 256; ++blk) {
    s += ps[blk * 128 + c];
    ss += pss[blk * 128 + c];
  }
  float m = s * (1.0f / 32768.0f);
  float v = ss * (1.0f / 32768.0f) - m * m;
  mu[tid] = m;
  rs[tid] = rsqrtf(v + 1e-5f);
}

// ---------------------------------------------------------------------------
// K3: 1x1 GEMM via bf16 MFMA, register-only.
// PRE: 0 none | 1 gelu(inorm)   AB16: A dtype (0 fp32, 1 bf16)
// POST: 0 fp32 store | 1 sigmoid*x -> bf16 store | 2 bf16 store
// STATS: fused per-block column sums -> ps/pss
// Block: 128 tokens x 128 o; 4 waves 2x2. grid (O/128, NTOK/128)
// ---------------------------------------------------------------------------
template <int PRE, int AB16, int POST, int STATS>
__global__ __launch_bounds__(256) void gemm_mfma_kernel(
    const void* __restrict__ Avoid, const unsigned short* __restrict__ Wp,
    const float* __restrict__ bias, void* __restrict__ Yvoid, int O,
    const float* __restrict__ mu, const float* __restrict__ rs,
    const float* __restrict__ xt, float* __restrict__ ps, float* __restrict__ pss) {
  __shared__ float sumb[128][2];
  __shared__ float sqb[128][2];
  const int tid = threadIdx.x;
  const int lane = tid & 63, wid = tid >> 6;
  const int wm = wid >> 1, wn = wid & 1;
  const int l15 = lane & 15, l4 = lane >> 4;
  const int og = blockIdx.x * 128;
  const int t0 = blockIdx.y * 128;
  const int bidx = t0 >> 15;
  const float* Af = (const float*)Avoid;
  const unsigned short* Ab = (const unsigned short*)Avoid;
  float* Yf = (float*)Yvoid;
  unsigned short* Yb = (unsigned short*)Yvoid;

  f32x4 acc[4][4];
  #pragma unroll
  for (int mt = 0; mt < 4; ++mt)
    #pragma unroll
    for (int nt = 0; nt < 4; ++nt)
      #pragma unroll
      for (int r = 0; r < 4; ++r) acc[mt][nt][r] = 0.f;

  #pragma unroll
  for (int ks = 0; ks < 4; ++ks) {
    const int kb = ks * 32 + l4 * 8;
    short8 a[4], bfr[4];
    float4 m0, m1, r0, r1;
    if constexpr (PRE == 1) {
      m0 = *(const float4*)(mu + bidx * 128 + kb);
      m1 = *(const float4*)(mu + bidx * 128 + kb + 4);
      r0 = *(const float4*)(rs + bidx * 128 + kb);
      r1 = *(const float4*)(rs + bidx * 128 + kb + 4);
    }
    #pragma unroll
    for (int mt = 0; mt < 4; ++mt) {
      const int tok = t0 + wm * 64 + mt * 16 + l15;
      if constexpr (AB16 == 1) {
        a[mt] = *(const short8*)(Ab + (size_t)tok * 128 + kb);
      } else {
        const float* ap = Af + (size_t)tok * 128 + kb;
        float4 v0 = *(const float4*)ap;
        float4 v1 = *(const float4*)(ap + 4);
        if constexpr (PRE == 1) {
          v0.x = gelu_f((v0.x - m0.x) * r0.x);
          v0.y = gelu_f((v0.y - m0.y) * r0.y);
          v0.z = gelu_f((v0.z - m0.z) * r0.z);
          v0.w = gelu_f((v0.w - m0.w) * r0.w);
          v1.x = gelu_f((v1.x - m1.x) * r1.x);
          v1.y = gelu_f((v1.y - m1.y) * r1.y);
          v1.z = gelu_f((v1.z - m1.z) * r1.z);
          v1.w = gelu_f((v1.w - m1.w) * r1.w);
        }
        a[mt] = pack_bf8(v0, v1);
      }
    }
    #pragma unroll
    for (int nt = 0; nt < 4; ++nt) {
      const int o = og + wn * 64 + nt * 16 + l15;
      bfr[nt] = *(const short8*)(Wp + (size_t)o * 128 + kb);
    }
    #pragma unroll
    for (int mt = 0; mt < 4; ++mt)
      #pragma unroll
      for (int nt = 0; nt < 4; ++nt)
        acc[mt][nt] = __builtin_amdgcn_mfma_f32_16x16x32_bf16(a[mt], bfr[nt], acc[mt][nt], 0, 0, 0);
  }

  #pragma unroll
  for (int nt = 0; nt < 4; ++nt) {
    const int o = og + wn * 64 + nt * 16 + l15;
    const float bb = bias[o];
    float s = 0.f, q = 0.f;
    #pragma unroll
    for (int mt = 0; mt < 4; ++mt) {
      #pragma unroll
      for (int r = 0; r < 4; ++r) {
        const int t = t0 + wm * 64 + mt * 16 + l4 * 4 + r;
        const float v = acc[mt][nt][r] + bb;
        if constexpr (POST == 0) {
          Yf[(size_t)t * O + o] = v;
        } else if constexpr (POST == 1) {
          Yb[(size_t)t * 128 + o] = f2bf(sigmoid_f(v) * xt[(size_t)t * 128 + o]);
        } else {
          Yb[(size_t)t * O + o] = f2bf(v);
        }
        if constexpr (STATS) { s += v; q += v * v; }
      }
    }
    if constexpr (STATS) {
      s += __shfl_xor(s, 16); s += __shfl_xor(s, 32);
      q += __shfl_xor(q, 16); q += __shfl_xor(q, 32);
      if (l4 == 0) { sumb[o - og][wm] = s; sqb[o - og][wm] = q; }
    }
  }
  if constexpr (STATS) {
    __syncthreads();
    if (tid < 128) {
      ps[blockIdx.y * 128 + tid] = sumb[tid][0] + sumb[tid][1];
      pss[blockIdx.y * 128 + tid] = sqb[tid][0] + sqb[tid][1];
    }
  }
}

// ---------------------------------------------------------------------------
// K6: final projection, swapped orientation -> coalesced NCDHW stores
// ---------------------------------------------------------------------------
__global__ __launch_bounds__(256) void proj_mfma_kernel(
    const float* __restrict__ Acc, const unsigned short* __restrict__ Wp,
    const float* __restrict__ bias, float* __restrict__ out) {
  const int tid = threadIdx.x;
  const int lane = tid & 63, wid = tid >> 6;
  const int wm = wid >> 1, wn = wid & 1;  // wm: o half, wn: token half
  const int l15 = lane & 15, l4 = lane >> 4;
  const int t0 = blockIdx.x * 128;

  f32x4 acc[4][4];
  #pragma unroll
  for (int mt = 0; mt < 4; ++mt)
    #pragma unroll
    for (int nt = 0; nt < 4; ++nt)
      #pragma unroll
      for (int r = 0; r < 4; ++r) acc[mt][nt][r] = 0.f;

  #pragma unroll
  for (int ks = 0; ks < 4; ++ks) {
    const int kb = ks * 32 + l4 * 8;
    short8 a[4], bfr[4];
    #pragma unroll
    for (int mt = 0; mt < 4; ++mt) {
      const int o = wm * 64 + mt * 16 + l15;
      a[mt] = *(const short8*)(Wp + (size_t)o * 128 + kb);
    }
    #pragma unroll
    for (int nt = 0; nt < 4; ++nt) {
      const int tok = t0 + wn * 64 + nt * 16 + l15;
      const float* bp = Acc + (size_t)tok * 128 + kb;
      bfr[nt] = pack_bf8(*(const float4*)bp, *(const float4*)(bp + 4));
    }
    #pragma unroll
    for (int mt = 0; mt < 4; ++mt)
      #pragma unroll
      for (int nt = 0; nt < 4; ++nt)
        acc[mt][nt] = __builtin_amdgcn_mfma_f32_16x16x32_bf16(a[mt], bfr[nt], acc[mt][nt], 0, 0, 0);
  }

  #pragma unroll
  for (int nt = 0; nt < 4; ++nt) {
    const int tok = t0 + wn * 64 + nt * 16 + l15;
    const int dhw = tok & 32767, bB = tok >> 15;
    #pragma unroll
    for (int mt = 0; mt < 4; ++mt) {
      #pragma unroll
      for (int r = 0; r < 4; ++r) {
        const int o = wm * 64 + mt * 16 + l4 * 4 + r;
        out[((size_t)(bB * 128 + o) << 15) + dhw] = acc[mt][nt][r] + bias[o];
      }
    }
  }
}

// ---------------------------------------------------------------------------
// K7: axial attention (bf16 qkv in, fp32 math, fp32 accum out).
// Effective logit: q_r.k_r * 0.25 - lin[k] * pos_bias_w[comp]
// ---------------------------------------------------------------------------
__device__ __forceinline__ void rot16(const float* R, const float* x, float* y) {
  #pragma unroll
  for (int g = 0; g < 5; ++g) {
    float a = x[3 * g], b = x[3 * g + 1], c = x[3 * g + 2];
    y[3 * g + 0] = R[0] * a + R[1] * b + R[2] * c;
    y[3 * g + 1] = R[3] * a + R[4] * b + R[5] * c;
    y[3 * g + 2] = R[6] * a + R[7] * b + R[8] * c;
  }
  y[15] = R[0] * x[15];  // padded vector (x15,0,0): only row0 col0 survives
}

template <int ACCUM>
__global__ __launch_bounds__(64) void attn_kernel(const unsigned short* __restrict__ qkv,
                                                  const float* __restrict__ Rbuf,
                                                  const float* __restrict__ pbw,
                                                  float* __restrict__ accum, int axial) {
  __shared__ float Klds[2][32][20];
  __shared__ float Vlds[2][32][20];
  int seq = blockIdx.x, hp = blockIdx.y;
  int lane = threadIdx.x;
  int hh = lane >> 5;
  int head = hp * 2 + hh;
  int tok = lane & 31;
  int b = seq >> 10, rem = seq & 1023;
  int u = rem >> 5, v = rem & 31;
  int base, stride, comp;
  if (axial == 0) { base = (b << 15) + (u << 5) + v;  stride = 1024; comp = 2; }
  else if (axial == 1) { base = (b << 15) + (u << 10) + v; stride = 32; comp = 1; }
  else { base = (b << 15) + (u << 10) + (v << 5); stride = 1; comp = 0; }
  const float* Rp = Rbuf + (axial * 8 + head) * 18;
  float Rq[9], Rv[9];
  #pragma unroll
  for (int i = 0; i < 9; ++i) { Rq[i] = Rp[i]; Rv[i] = Rp[9 + i]; }
  size_t t_tok = (size_t)base + (size_t)tok * stride;
  const unsigned short* row = qkv + t_tok * 384 + head * 16;
  float xq[16], xk[16], xv[16];
  bf16x16_load(row, xq);
  bf16x16_load(row + 128, xk);
  bf16x16_load(row + 256, xv);
  float qr[16], kr[16], vr[16];
  rot16(Rq, xq, qr);
  rot16(Rq, xk, kr);
  rot16(Rv, xv, vr);
  #pragma unroll
  for (int j = 0; j < 16; ++j) { Klds[hh][tok][j] = kr[j]; Vlds[hh][tok][j] = vr[j]; }
  __syncthreads();
  float wb = pbw[comp];
  float s[32];
  #pragma unroll
  for (int k = 0; k < 32; ++k) {
    const float* kp = &Klds[hh][k][0];
    float dot = 0.f;
    #pragma unroll
    for (int j = 0; j < 16; ++j) dot += qr[j] * kp[j];
    float lin = -1.0f + (2.0f / 31.0f) * (float)k;
    s[k] = dot * 0.25f - lin * wb;
  }
  float m = s[0];
  #pragma unroll
  for (int k = 1; k < 32; ++k) m = fmaxf(m, s[k]);
  float sum = 0.f;
  #pragma unroll
  for (int k = 0; k < 32; ++k) { s[k] = expf(s[k] - m); sum += s[k]; }
  float inv = 1.0f / sum;
  float o[16];
  #pragma unroll
  for (int j = 0; j < 16; ++j) o[j] = 0.f;
  #pragma unroll
  for (int k = 0; k < 32; ++k) {
    float p = s[k];
    const float* vp = &Vlds[hh][k][0];
    #pragma unroll
    for (int j = 0; j < 16; ++j) o[j] += p * vp[j];
  }
  float* dst = accum + t_tok * 128 + head * 16;
  if (ACCUM == 0) {
    #pragma unroll
    for (int j = 0; j < 16; ++j) dst[j] = o[j] * inv;
  } else {
    #pragma unroll
    for (int j = 0; j < 16; ++j) dst[j] += o[j] * inv;
  }
}

// ---------------------------------------------------------------------------
extern "C" void kernel_launch(void* const* d_in, const int* in_sizes, int n_in,
                              void* d_out, int out_size, void* d_ws, size_t ws_size,
                              hipStream_t stream) {
  const float* x       = (const float*)d_in[0];
  const float* pos_emb = (const float*)d_in[1];
  const float* qkv_w   = (const float*)d_in[2];
  const float* qkv_b   = (const float*)d_in[3];
  const float* lp_w1   = (const float*)d_in[4];
  const float* lp_b1   = (const float*)d_in[5];
  const float* lp_w2   = (const float*)d_in[6];
  const float* lp_b2   = (const float*)d_in[7];
  const float* mod_w1  = (const float*)d_in[8];
  const float* mod_b1  = (const float*)d_in[9];
  const float* mod_w2  = (const float*)d_in[10];
  const float* mod_b2  = (const float*)d_in[11];
  // d_in[12] pa_w, d_in[13] pa_b: cancel in softmax (constant along key axis)
  const float* proj_w  = (const float*)d_in[14];
  const float* proj_b  = (const float*)d_in[15];
  const float* pbw     = (const float*)d_in[16];
  // d_in[17] pos_bias_b: cancels in softmax
  const float* Ad      = (const float*)d_in[18];
  const float* Ah      = (const float*)d_in[19];
  const float* Aw      = (const float*)d_in[20];
  const float* Rd      = (const float*)d_in[21];
  const float* Rh      = (const float*)d_in[22];
  const float* Rw      = (const float*)d_in[23];
  // d_in[24..26] t_d/t_h/t_w: cancel in rel (pairwise difference)

  float* ws = (float*)d_ws;
  float* R0     = ws + WS_R0;     // lf -> attn accum
  float* mpre   = ws + WS_MPRE;
  float* xtok   = ws + WS_XTOK;
  unsigned short* inT    = (unsigned short*)(ws + WS_INT);   // pos_emb bf16 -> x_mod bf16
  unsigned short* qkvb   = (unsigned short*)(ws + WS_QKVB);
  unsigned short* convP  = (unsigned short*)(ws + WS_CONVP);
  unsigned short* qkvP   = (unsigned short*)(ws + WS_QKVP);
  unsigned short* WcP    = (unsigned short*)(ws + WS_WCP);
  unsigned short* modw2P = (unsigned short*)(ws + WS_MODW2P);
  unsigned short* projP  = (unsigned short*)(ws + WS_PROJP);
  float* bc     = ws + WS_BC;
  float* Rbuf   = ws + WS_RBUF;
  float* ps     = ws + WS_PS;
  float* pss    = ws + WS_PSS;
  float* mu1    = ws + WS_MU1;
  float* rs1    = ws + WS_RS1;
  float* mu2    = ws + WS_MU2;
  float* rs2    = ws + WS_RS2;
  unsigned short* xmodb = inT;  // x_mod bf16 reuses INT region (inT dead after conv)

  prep_r_kernel<<<1, 64, 0, stream>>>(Ad, Ah, Aw, Rd, Rh, Rw, Rbuf);
  prep_w_kernel<<<256, 256, 0, stream>>>(lp_w1, qkv_w, mod_w1, lp_w2, lp_b2, mod_b1,
                                         mod_w2, proj_w, convP, qkvP, WcP, modw2P, projP, bc);
  transpose_kernel<<<2048, 256, 0, stream>>>(x, pos_emb, xtok, inT);
  // lf = circular conv3x3x3(pos_emb), fused stats partials
  conv_mfma_kernel<<<512, 512, 0, stream>>>(inT, convP, lp_b1, R0, ps, pss);
  stats_final_kernel<<<1, 256, 0, stream>>>(ps, pss, mu1, rs1);
  // m_pre = gelu(inorm(lf)) @ Wc^T + bc, fused stats partials
  gemm_mfma_kernel<1, 0, 0, 1><<<dim3(1, 512), 256, 0, stream>>>(
      R0, WcP, bc, mpre, 128, mu1, rs1, nullptr, ps, pss);
  stats_final_kernel<<<1, 256, 0, stream>>>(ps, pss, mu2, rs2);
  // x_mod (bf16) = x * sigmoid(gelu(inorm(m_pre)) @ mod_w2^T + mod_b2)
  gemm_mfma_kernel<1, 0, 1, 0><<<dim3(1, 512), 256, 0, stream>>>(
      mpre, modw2P, mod_b2, xmodb, 128, mu2, rs2, xtok, nullptr, nullptr);
  // qkv (bf16) = x_mod @ qkv_w^T + qkv_b
  gemm_mfma_kernel<0, 1, 2, 0><<<dim3(3, 512), 256, 0, stream>>>(
      xmodb, qkvP, qkv_b, qkvb, 384, nullptr, nullptr, nullptr, nullptr, nullptr);
  // three axial attentions, accumulated into R0
  attn_kernel<0><<<dim3(2048, 4), 64, 0, stream>>>(qkvb, Rbuf, pbw, R0, 0);
  attn_kernel<1><<<dim3(2048, 4), 64, 0, stream>>>(qkvb, Rbuf, pbw, R0, 1);
  attn_kernel<1><<<dim3(2048, 4), 64, 0, stream>>>(qkvb, Rbuf, pbw, R0, 2);
  // final projection -> NCDHW output (swapped orientation, coalesced stores)
  proj_mfma_kernel<<<512, 256, 0, stream>>>(R0, projP, proj_b, (float*)d_out);
}

// Round 5
// 488.164 us; speedup vs baseline: 1.2542x; 1.2542x over previous
//
#include <hip/hip_runtime.h>
#include <cstdint>
#include <cstddef>

// ---------------------------------------------------------------------------
// Problem constants: B=2, C=128, D=H=W=32, nh=8, hd=16, L=32
// Tokens: t = b*32768 + d*1024 + h*32 + w   (65536 tokens, 128 channels)
// ---------------------------------------------------------------------------

#define NTOK 65536
#define SPAT 32768

// ws offsets (floats). Timeline:
//   transpose: writes XTOK (fp32 x) + INT (bf16 pos_emb)
//   conv:      reads INT, writes R0 (lf fp32) + stats
//   gemmWc:    reads R0, writes MPRE + stats          (R0 dead after)
//   gemmGate:  reads MPRE+XTOK, writes XMODB=INT      (MPRE,XTOK dead after)
//   gemmQKV:   reads XMODB, writes QKVH (head-major bf16, overlays MPRE+XTOK[:half])
//   attn:      reads QKVH, writes A0,A1,A2 (bf16; A0/A1 overlay dead R0, A2 after QKVH)
//   proj:      reads A0+A1+A2 -> d_out
#define WS_R0     0ull          // 8388608 fp32
#define WS_A0     0ull          // 4194304 (8388608 ush)
#define WS_A1     4194304ull    // 4194304
#define WS_MPRE   8388608ull    // 8388608 fp32
#define WS_QKVH   8388608ull    // 12582912 (25165824 ush) [h][t][48]
#define WS_XTOK   16777216ull   // 8388608 fp32
#define WS_A2     20971520ull   // 4194304 (8388608 ush)
#define WS_INT    25165824ull   // 4194304 (8388608 ush): pos_emb bf16 -> x_mod bf16
#define WS_CONVP  29360128ull   // 221184 (442368 ush)
#define WS_QKVP   29581312ull   // 24576  (49152 ush)
#define WS_WCP    29605888ull   // 8192
#define WS_MODW2P 29614080ull   // 8192
#define WS_PROJP  29622272ull   // 8192
#define WS_BC     29630464ull   // 128
#define WS_RBUF   29630592ull   // 432
#define WS_PS     29631024ull   // 65536
#define WS_PSS    29696560ull   // 65536
#define WS_MU1    29762096ull   // 256
#define WS_RS1    29762352ull   // 256
#define WS_MU2    29762608ull   // 256
#define WS_RS2    29762864ull   // 256
// total 29763120 floats = 119.1 MB

typedef __attribute__((ext_vector_type(8))) short short8;
typedef __attribute__((ext_vector_type(4))) float f32x4;

__device__ __forceinline__ float gelu_f(float x) {
  return 0.5f * x * (1.0f + erff(x * 0.70710678118654752f));
}
__device__ __forceinline__ float sigmoid_f(float x) {
  return 1.0f / (1.0f + expf(-x));
}
__device__ __forceinline__ unsigned short f2bf(float x) {  // RNE f32->bf16
  unsigned int u = __float_as_uint(x);
  unsigned int r = u + 0x7fffu + ((u >> 16) & 1u);
  return (unsigned short)(r >> 16);
}
__device__ __forceinline__ float bf2f(unsigned short u) {
  return __uint_as_float(((unsigned int)u) << 16);
}
__device__ __forceinline__ short8 pack_bf8(float4 v0, float4 v1) {
  short8 r;
  r[0] = (short)f2bf(v0.x); r[1] = (short)f2bf(v0.y);
  r[2] = (short)f2bf(v0.z); r[3] = (short)f2bf(v0.w);
  r[4] = (short)f2bf(v1.x); r[5] = (short)f2bf(v1.y);
  r[6] = (short)f2bf(v1.z); r[7] = (short)f2bf(v1.w);
  return r;
}
// 16 consecutive bf16 -> 16 fp32
__device__ __forceinline__ void bf16x16_load(const unsigned short* p, float* f) {
  const uint4 a = *(const uint4*)p;
  const uint4 b = *(const uint4*)(p + 8);
  const unsigned int w[8] = {a.x, a.y, a.z, a.w, b.x, b.y, b.z, b.w};
  #pragma unroll
  for (int i = 0; i < 8; ++i) {
    f[2 * i] = __uint_as_float(w[i] << 16);
    f[2 * i + 1] = __uint_as_float(w[i] & 0xffff0000u);
  }
}
// async global->LDS, 16B per lane (dest must be wave-uniform base + lane*16)
__device__ __forceinline__ void gload_lds16(const void* g, void* l) {
  __builtin_amdgcn_global_load_lds(
      (const __attribute__((address_space(1))) unsigned int*)g,
      (__attribute__((address_space(3))) unsigned int*)l, 16, 0, 0);
}
__device__ __forceinline__ float dot3(const float* a, const float* b) {
  return a[0] * b[0] + a[1] * b[1] + a[2] * b[2];
}
__device__ __forceinline__ void cross3(const float* a, const float* b, float* c) {
  c[0] = a[1] * b[2] - a[2] * b[1];
  c[1] = a[2] * b[0] - a[0] * b[2];
  c[2] = a[0] * b[1] - a[1] * b[0];
}

// exact port of _r6_to_matrix for one head (6 floats in, 9 out row-major)
__device__ void r6_to_matrix(const float* r6, float* R) {
  float v1[3] = {r6[0], r6[1], r6[2]};
  float n1 = sqrtf(dot3(v1, v1));
  float inv1 = 1.0f / (n1 + 1e-7f);
  v1[0] *= inv1; v1[1] *= inv1; v1[2] *= inv1;
  float v2[3] = {r6[3], r6[4], r6[5]};
  float d = dot3(v2, v1);
  v2[0] -= d * v1[0]; v2[1] -= d * v1[1]; v2[2] -= d * v1[2];
  float n2 = sqrtf(dot3(v2, v2));
  float inv2 = 1.0f / (n2 + 1e-7f);
  v2[0] *= inv2; v2[1] *= inv2; v2[2] *= inv2;
  float v3[3]; cross3(v1, v2, v3);
  float cx[3]; cross3(v2, v3, cx);
  float det = dot3(v1, cx);
  if (det < 0.0f) { v3[0] = -v3[0]; v3[1] = -v3[1]; v3[2] = -v3[2]; }
  R[0] = v1[0]; R[1] = v1[1]; R[2] = v1[2];
  R[3] = v2[0]; R[4] = v2[1]; R[5] = v2[2];
  R[6] = v3[0]; R[7] = v3[1]; R[8] = v3[2];
}

// exact port of _ensure_matrix for one head (9 in row-major, 9 out)
__device__ void ensure_matrix(const float* Rin, float* Ro) {
  float a[3] = {Rin[0] + 1e-6f, Rin[1] + 1e-6f, Rin[2] + 1e-6f};
  float na = fmaxf(sqrtf(dot3(a, a)), 1e-12f);
  float v1[3] = {a[0] / na, a[1] / na, a[2] / na};
  float b0[3] = {Rin[3], Rin[4], Rin[5]};
  float d = dot3(b0, v1);
  float bb[3] = {b0[0] - d * v1[0] + 1e-6f, b0[1] - d * v1[1] + 1e-6f, b0[2] - d * v1[2] + 1e-6f};
  float nb = fmaxf(sqrtf(dot3(bb, bb)), 1e-12f);
  float v2[3] = {bb[0] / nb, bb[1] / nb, bb[2] / nb};
  float v3[3]; cross3(v1, v2, v3);
  float cx[3]; cross3(v2, v3, cx);
  float det = dot3(v1, cx);
  if (det < 0.0f) { v3[0] = -v3[0]; v3[1] = -v3[1]; v3[2] = -v3[2]; }
  float Rn[9] = {v1[0], v1[1], v1[2], v2[0], v2[1], v2[2], v3[0], v3[1], v3[2]};
  float T1[9], T2[9];
  for (int i = 0; i < 3; ++i)
    for (int j = 0; j < 3; ++j) {
      float s = 0.f;
      for (int k = 0; k < 3; ++k) s += Rn[k * 3 + i] * Rn[k * 3 + j];
      T1[i * 3 + j] = s;
    }
  for (int i = 0; i < 3; ++i)
    for (int j = 0; j < 3; ++j) {
      float s = 0.f;
      for (int k = 0; k < 3; ++k) s += T1[i * 3 + k] * Rn[j * 3 + k];
      T2[i * 3 + j] = s;
    }
  for (int i = 0; i < 9; ++i) Ro[i] = 0.5f * (Rn[i] + T2[i]);
}

// ---------------------------------------------------------------------------
// K0: rotation matrices for 3 axials x 8 heads
// ---------------------------------------------------------------------------
__global__ void prep_r_kernel(const float* __restrict__ Ad, const float* __restrict__ Ah,
                              const float* __restrict__ Aw, const float* __restrict__ Rd,
                              const float* __restrict__ Rh, const float* __restrict__ Rw,
                              float* __restrict__ Rbuf) {
  int tid = threadIdx.x;
  if (tid >= 24) return;
  int ax = tid >> 3, h = tid & 7;
  const float* A = (ax == 0) ? Ad : ((ax == 1) ? Ah : Aw);
  const float* R = (ax == 0) ? Rd : ((ax == 1) ? Rh : Rw);
  float Rq[9], Rv[9];
  r6_to_matrix(A + h * 6, Rq);
  ensure_matrix(R + h * 9, Rv);
  float* dst = Rbuf + (ax * 8 + h) * 18;
  for (int i = 0; i < 9; ++i) { dst[i] = Rq[i]; dst[9 + i] = Rv[i]; }
}

// ---------------------------------------------------------------------------
// K0b: bf16 weight packs + fused (mod_w1 @ lp_w2) matrix
// ---------------------------------------------------------------------------
__global__ __launch_bounds__(256) void prep_w_kernel(
    const float* __restrict__ lp_w1, const float* __restrict__ qkv_w,
    const float* __restrict__ mod_w1, const float* __restrict__ lp_w2,
    const float* __restrict__ lp_b2, const float* __restrict__ mod_b1,
    const float* __restrict__ mod_w2, const float* __restrict__ proj_w,
    unsigned short* __restrict__ convP, unsigned short* __restrict__ qkvP,
    unsigned short* __restrict__ WcP, unsigned short* __restrict__ modw2P,
    unsigned short* __restrict__ projP, float* __restrict__ bc) {
  int gid = blockIdx.x * 256 + threadIdx.x;  // 65536 threads
  for (int f = gid; f < 442368; f += 65536) {
    int ci = f & 127;
    int rr = f >> 7;        // (tap*128+co)*3 + dx
    int dx = rr % 3;
    int r2 = rr / 3;
    int co = r2 & 127;
    int tap = r2 >> 7;
    int dz = tap / 3, dy = tap % 3;
    convP[f] = f2bf(lp_w1[(co * 128 + ci) * 27 + dz * 9 + dy * 3 + dx]);
  }
  if (gid < 49152) qkvP[gid] = f2bf(qkv_w[gid]);
  if (gid < 16384) {
    modw2P[gid] = f2bf(mod_w2[gid]);
    projP[gid] = f2bf(proj_w[gid]);
    int o = gid >> 7, i = gid & 127;
    float s = 0.f;
    for (int c = 0; c < 128; ++c) s += mod_w1[o * 128 + c] * lp_w2[c * 128 + i];
    WcP[gid] = f2bf(s);
  }
  if (gid < 128) {
    float s = 0.f;
    for (int c = 0; c < 128; ++c) s += mod_w1[gid * 128 + c] * lp_b2[c];
    bc[gid] = s + mod_b1[gid];
  }
}

// ---------------------------------------------------------------------------
// K0c: merged transposes. Per (b,d,h) plane: x -> xtok fp32, pos_emb -> inT bf16
// ---------------------------------------------------------------------------
__global__ __launch_bounds__(256) void transpose_kernel(const float* __restrict__ x,
                                                        const float* __restrict__ pe,
                                                        float* __restrict__ xtok,
                                                        unsigned short* __restrict__ inT) {
  __shared__ float lds[32][132];
  int blk = blockIdx.x;  // b*1024 + d*32 + h
  int b = blk >> 10;
  int dh = blk & 1023;
  int tid = threadIdx.x;
  size_t planebase = ((size_t)b << 22) + ((size_t)dh << 5);
  size_t tb = ((size_t)blk) << 5;
  #pragma unroll
  for (int r = 0; r < 16; ++r) {
    int idx = r * 256 + tid;
    int ci = idx >> 5, w = idx & 31;
    lds[w][ci] = x[planebase + ((size_t)ci << 15) + w];
  }
  __syncthreads();
  #pragma unroll
  for (int r = 0; r < 16; ++r) {
    int idx = r * 256 + tid;
    int w = idx >> 7, ci = idx & 127;
    xtok[(tb + w) * 128 + ci] = lds[w][ci];
  }
  __syncthreads();
  #pragma unroll
  for (int r = 0; r < 16; ++r) {
    int idx = r * 256 + tid;
    int ci = idx >> 5, w = idx & 31;
    lds[w][ci] = pe[planebase + ((size_t)ci << 15) + w];
  }
  __syncthreads();
  #pragma unroll
  for (int r = 0; r < 16; ++r) {
    int idx = r * 256 + tid;
    int w = idx >> 7, ci = idx & 127;
    inT[(tb + w) * 128 + ci] = f2bf(lds[w][ci]);
  }
}

// ---------------------------------------------------------------------------
// K1: 3x3x3 circular conv via bf16 MFMA, v3.
// r3 proven structure (256 thr, 2x2 waves, 64x64/wave, per-tap 32KB A-tile)
// + double-buffered LDS + async global_load_lds staging (2-phase pipeline).
// Fused instance-norm partial stats in epilogue.
// ---------------------------------------------------------------------------
__global__ __launch_bounds__(256, 2) void conv_mfma_kernel(
    const unsigned short* __restrict__ inT, const unsigned short* __restrict__ Bp,
    const float* __restrict__ b1, float* __restrict__ out,
    float* __restrict__ ps, float* __restrict__ pss) {
  __shared__ unsigned short Als[2][16384];  // 2 x 32KB, source-swizzled
  __shared__ float sumb[128][2];
  __shared__ float sqb[128][2];
  const int blk = blockIdx.x;
  const int b = blk >> 8, d = (blk >> 3) & 31, hg = blk & 7;
  const int h0 = hg << 2;
  const int tid = threadIdx.x;
  const int lane = tid & 63;
  const int wid = tid >> 6;
  const int wm = wid >> 1, wn = wid & 1;
  const int l15 = lane & 15, l4 = lane >> 4;

  f32x4 acc[4][4];
  #pragma unroll
  for (int mt = 0; mt < 4; ++mt)
    #pragma unroll
    for (int nt = 0; nt < 4; ++nt)
      #pragma unroll
      for (int r = 0; r < 4; ++r) acc[mt][nt][r] = 0.f;

  int mw[4], mhh[4];
  #pragma unroll
  for (int mt = 0; mt < 4; ++mt) {
    int m = wm * 64 + mt * 16 + l15;
    mhh[mt] = m >> 5;
    mw[mt] = m & 31;
  }
  const size_t tokbase = ((size_t)b << 15) + ((size_t)d << 10) + ((size_t)h0 << 5);

  // async stage of one tap's 128tok x 128ci bf16 tile into Als[buf]
  auto stage = [&](int buf, int tap) {
    const int dz = tap / 3, dy = tap % 3;
    const int zr = (d + dz + 31) & 31;
    #pragma unroll
    for (int p = 0; p < 8; ++p) {
      const int g = p * 256 + tid;
      const int tok = g >> 4, gi = g & 15;
      const int hh = tok >> 5, w = tok & 31;
      const int yr = (h0 + hh + dy + 31) & 31;
      const size_t srcbyte = ((((size_t)b << 15) + ((size_t)zr << 10) + ((size_t)yr << 5) + w) << 8)
                             + (size_t)((gi ^ (w & 7)) << 4);
      gload_lds16((const char*)inT + srcbyte, (char*)&Als[buf][0] + (size_t)g * 16);
    }
  };

  // MFMA phase for dx in [dxa, dxb)
  auto computeDx = [&](int buf, int tap, int dxa, int dxb) {
    int brow[4];
    #pragma unroll
    for (int nt = 0; nt < 4; ++nt) {
      const int co = wn * 64 + nt * 16 + l15;
      brow[nt] = (tap * 128 + co) * 384;
    }
    for (int dx = dxa; dx < dxb; ++dx) {
      int abase[4], asw[4];
      #pragma unroll
      for (int mt = 0; mt < 4; ++mt) {
        const int wsft = (mw[mt] + dx + 31) & 31;
        const int stok = mhh[mt] * 32 + wsft;
        abase[mt] = stok * 256;
        asw[mt] = (wsft & 7) << 4;
      }
      #pragma unroll
      for (int ks = 0; ks < 4; ++ks) {
        const int k2 = (ks * 32 + l4 * 8) * 2;
        const int koff = dx * 128 + ks * 32 + l4 * 8;
        short8 afr[4], bfr[4];
        #pragma unroll
        for (int nt = 0; nt < 4; ++nt)
          bfr[nt] = *(const short8*)(Bp + brow[nt] + koff);
        #pragma unroll
        for (int mt = 0; mt < 4; ++mt)
          afr[mt] = *(const short8*)((const char*)&Als[buf][0] + abase[mt] + (k2 ^ asw[mt]));
        #pragma unroll
        for (int mt = 0; mt < 4; ++mt)
          #pragma unroll
          for (int nt = 0; nt < 4; ++nt)
            acc[mt][nt] = __builtin_amdgcn_mfma_f32_16x16x32_bf16(afr[mt], bfr[nt],
                                                                  acc[mt][nt], 0, 0, 0);
      }
    }
  };

  stage(0, 0);
  __syncthreads();  // implicit vmcnt(0) drain: tile 0 ready
  int cur = 0;
  for (int tap = 0; tap < 9; ++tap) {
    computeDx(cur, tap, 0, 1);          // dx=0: B loads issued before stage
    if (tap < 8) stage(cur ^ 1, tap + 1);  // async into other buffer
    computeDx(cur, tap, 1, 3);          // dx=1,2 hide stage latency
    __syncthreads();                    // drains vmcnt: next tile ready, reads done
    cur ^= 1;
  }

  // epilogue: bias + store + fused stats partials
  #pragma unroll
  for (int nt = 0; nt < 4; ++nt) {
    const int co = wn * 64 + nt * 16 + l15;
    const float bias = b1[co];
    float s = 0.f, q = 0.f;
    #pragma unroll
    for (int mt = 0; mt < 4; ++mt) {
      #pragma unroll
      for (int r = 0; r < 4; ++r) {
        const int m = wm * 64 + mt * 16 + l4 * 4 + r;
        const float v = acc[mt][nt][r] + bias;
        out[(tokbase + m) * 128 + co] = v;
        s += v; q += v * v;
      }
    }
    s += __shfl_xor(s, 16); s += __shfl_xor(s, 32);
    q += __shfl_xor(q, 16); q += __shfl_xor(q, 32);
    if (l4 == 0) { sumb[co][wm] = s; sqb[co][wm] = q; }
  }
  __syncthreads();
  if (tid < 128) {
    ps[blk * 128 + tid] = sumb[tid][0] + sumb[tid][1];
    pss[blk * 128 + tid] = sqb[tid][0] + sqb[tid][1];
  }
}

// ---------------------------------------------------------------------------
// K2: stats finalize (512 partial blocks, 256 per batch)
// ---------------------------------------------------------------------------
__global__ void stats_final_kernel(const float* __restrict__ ps, const float* __restrict__ pss,
                                   float* __restrict__ mu, float* __restrict__ rs) {
  int tid = threadIdx.x;  // tid = b*128 + c
  int b = tid >> 7, c = tid & 127;
  float s = 0.f, ss = 0.f;
  for (int blk = b * 256; blk < b * 256 + 256; ++blk) {
    s += ps[blk * 128 + c];
    ss += pss[blk * 128 + c];
  }
  float m = s * (1.0f / 32768.0f);
  float v = ss * (1.0f / 32768.0f) - m * m;
  mu[tid] = m;
  rs[tid] = rsqrtf(v + 1e-5f);
}

// ---------------------------------------------------------------------------
// K3: 1x1 GEMM via bf16 MFMA, register-only.
// PRE: 0 none | 1 gelu(inorm)   AB16: A dtype (0 fp32, 1 bf16)
// POST: 0 fp32 store | 1 sigmoid*x -> bf16 store | 2 bf16 head-major qkv store
// STATS: fused per-block column sums -> ps/pss
// Block: 128 tokens x 128 o; 4 waves 2x2. grid (O/128, NTOK/128)
// ---------------------------------------------------------------------------
template <int PRE, int AB16, int POST, int STATS>
__global__ __launch_bounds__(256) void gemm_mfma_kernel(
    const void* __restrict__ Avoid, const unsigned short* __restrict__ Wp,
    const float* __restrict__ bias, void* __restrict__ Yvoid, int O,
    const float* __restrict__ mu, const float* __restrict__ rs,
    const float* __restrict__ xt, float* __restrict__ ps, float* __restrict__ pss) {
  __shared__ float sumb[128][2];
  __shared__ float sqb[128][2];
  const int tid = threadIdx.x;
  const int lane = tid & 63, wid = tid >> 6;
  const int wm = wid >> 1, wn = wid & 1;
  const int l15 = lane & 15, l4 = lane >> 4;
  const int og = blockIdx.x * 128;
  const int t0 = blockIdx.y * 128;
  const int bidx = t0 >> 15;
  const float* Af = (const float*)Avoid;
  const unsigned short* Ab = (const unsigned short*)Avoid;
  float* Yf = (float*)Yvoid;
  unsigned short* Yb = (unsigned short*)Yvoid;

  f32x4 acc[4][4];
  #pragma unroll
  for (int mt = 0; mt < 4; ++mt)
    #pragma unroll
    for (int nt = 0; nt < 4; ++nt)
      #pragma unroll
      for (int r = 0; r < 4; ++r) acc[mt][nt][r] = 0.f;

  #pragma unroll
  for (int ks = 0; ks < 4; ++ks) {
    const int kb = ks * 32 + l4 * 8;
    short8 a[4], bfr[4];
    float4 m0, m1, r0, r1;
    if constexpr (PRE == 1) {
      m0 = *(const float4*)(mu + bidx * 128 + kb);
      m1 = *(const float4*)(mu + bidx * 128 + kb + 4);
      r0 = *(const float4*)(rs + bidx * 128 + kb);
      r1 = *(const float4*)(rs + bidx * 128 + kb + 4);
    }
    #pragma unroll
    for (int mt = 0; mt < 4; ++mt) {
      const int tok = t0 + wm * 64 + mt * 16 + l15;
      if constexpr (AB16 == 1) {
        a[mt] = *(const short8*)(Ab + (size_t)tok * 128 + kb);
      } else {
        const float* ap = Af + (size_t)tok * 128 + kb;
        float4 v0 = *(const float4*)ap;
        float4 v1 = *(const float4*)(ap + 4);
        if constexpr (PRE == 1) {
          v0.x = gelu_f((v0.x - m0.x) * r0.x);
          v0.y = gelu_f((v0.y - m0.y) * r0.y);
          v0.z = gelu_f((v0.z - m0.z) * r0.z);
          v0.w = gelu_f((v0.w - m0.w) * r0.w);
          v1.x = gelu_f((v1.x - m1.x) * r1.x);
          v1.y = gelu_f((v1.y - m1.y) * r1.y);
          v1.z = gelu_f((v1.z - m1.z) * r1.z);
          v1.w = gelu_f((v1.w - m1.w) * r1.w);
        }
        a[mt] = pack_bf8(v0, v1);
      }
    }
    #pragma unroll
    for (int nt = 0; nt < 4; ++nt) {
      const int o = og + wn * 64 + nt * 16 + l15;
      bfr[nt] = *(const short8*)(Wp + (size_t)o * 128 + kb);
    }
    #pragma unroll
    for (int mt = 0; mt < 4; ++mt)
      #pragma unroll
      for (int nt = 0; nt < 4; ++nt)
        acc[mt][nt] = __builtin_amdgcn_mfma_f32_16x16x32_bf16(a[mt], bfr[nt], acc[mt][nt], 0, 0, 0);
  }

  #pragma unroll
  for (int nt = 0; nt < 4; ++nt) {
    const int o = og + wn * 64 + nt * 16 + l15;
    const float bb = bias[o];
    float s = 0.f, q = 0.f;
    #pragma unroll
    for (int mt = 0; mt < 4; ++mt) {
      #pragma unroll
      for (int r = 0; r < 4; ++r) {
        const int t = t0 + wm * 64 + mt * 16 + l4 * 4 + r;
        const float v = acc[mt][nt][r] + bb;
        if constexpr (POST == 0) {
          Yf[(size_t)t * O + o] = v;
        } else if constexpr (POST == 1) {
          Yb[(size_t)t * 128 + o] = f2bf(sigmoid_f(v) * xt[(size_t)t * 128 + o]);
        } else {
          // head-major qkv: [h][t][48] with q|k|v 16-ch sections
          const int which = o >> 7, hsub = (o & 127) >> 4, ch = o & 15;
          Yb[((size_t)hsub * NTOK + t) * 48 + which * 16 + ch] = f2bf(v);
        }
        if constexpr (STATS) { s += v; q += v * v; }
      }
    }
    if constexpr (STATS) {
      s += __shfl_xor(s, 16); s += __shfl_xor(s, 32);
      q += __shfl_xor(q, 16); q += __shfl_xor(q, 32);
      if (l4 == 0) { sumb[o - og][wm] = s; sqb[o - og][wm] = q; }
    }
  }
  if constexpr (STATS) {
    __syncthreads();
    if (tid < 128) {
      ps[blockIdx.y * 128 + tid] = sumb[tid][0] + sumb[tid][1];
      pss[blockIdx.y * 128 + tid] = sqb[tid][0] + sqb[tid][1];
    }
  }
}

// ---------------------------------------------------------------------------
// K6: final projection over A0+A1+A2 (bf16), swapped orientation -> NCDHW
// ---------------------------------------------------------------------------
__global__ __launch_bounds__(256) void proj_mfma_kernel(
    const unsigned short* __restrict__ A0b, const unsigned short* __restrict__ A1b,
    const unsigned short* __restrict__ A2b, const unsigned short* __restrict__ Wp,
    const float* __restrict__ bias, float* __restrict__ out) {
  const int tid = threadIdx.x;
  const int lane = tid & 63, wid = tid >> 6;
  const int wm = wid >> 1, wn = wid & 1;  // wm: o half, wn: token half
  const int l15 = lane & 15, l4 = lane >> 4;
  const int t0 = blockIdx.x * 128;

  f32x4 acc[4][4];
  #pragma unroll
  for (int mt = 0; mt < 4; ++mt)
    #pragma unroll
    for (int nt = 0; nt < 4; ++nt)
      #pragma unroll
      for (int r = 0; r < 4; ++r) acc[mt][nt][r] = 0.f;

  #pragma unroll
  for (int ks = 0; ks < 4; ++ks) {
    const int kb = ks * 32 + l4 * 8;
    short8 a[4], bfr[4];
    #pragma unroll
    for (int mt = 0; mt < 4; ++mt) {
      const int o = wm * 64 + mt * 16 + l15;
      a[mt] = *(const short8*)(Wp + (size_t)o * 128 + kb);
    }
    #pragma unroll
    for (int nt = 0; nt < 4; ++nt) {
      const int tok = t0 + wn * 64 + nt * 16 + l15;
      const size_t off = (size_t)tok * 128 + kb;
      short8 s0 = *(const short8*)(A0b + off);
      short8 s1 = *(const short8*)(A1b + off);
      short8 s2 = *(const short8*)(A2b + off);
      short8 r;
      #pragma unroll
      for (int i = 0; i < 8; ++i) {
        float f = bf2f((unsigned short)s0[i]) + bf2f((unsigned short)s1[i]) +
                  bf2f((unsigned short)s2[i]);
        r[i] = (short)f2bf(f);
      }
      bfr[nt] = r;
    }
    #pragma unroll
    for (int mt = 0; mt < 4; ++mt)
      #pragma unroll
      for (int nt = 0; nt < 4; ++nt)
        acc[mt][nt] = __builtin_amdgcn_mfma_f32_16x16x32_bf16(a[mt], bfr[nt], acc[mt][nt], 0, 0, 0);
  }

  #pragma unroll
  for (int nt = 0; nt < 4; ++nt) {
    const int tok = t0 + wn * 64 + nt * 16 + l15;
    const int dhw = tok & 32767, bB = tok >> 15;
    #pragma unroll
    for (int mt = 0; mt < 4; ++mt) {
      #pragma unroll
      for (int r = 0; r < 4; ++r) {
        const int o = wm * 64 + mt * 16 + l4 * 4 + r;
        out[((size_t)(bB * 128 + o) << 15) + dhw] = acc[mt][nt][r] + bias[o];
      }
    }
  }
}

// ---------------------------------------------------------------------------
// K7: axial attention, all 3 axials in one dispatch (blockIdx.z = axial).
// qkv head-major bf16 [h][t][48]; per-axial bf16 output buffers (no RMW).
// Effective logit: q_r.k_r * 0.25 - lin[k] * pos_bias_w[comp]
// ---------------------------------------------------------------------------
__device__ __forceinline__ void rot16(const float* R, const float* x, float* y) {
  #pragma unroll
  for (int g = 0; g < 5; ++g) {
    float a = x[3 * g], b = x[3 * g + 1], c = x[3 * g + 2];
    y[3 * g + 0] = R[0] * a + R[1] * b + R[2] * c;
    y[3 * g + 1] = R[3] * a + R[4] * b + R[5] * c;
    y[3 * g + 2] = R[6] * a + R[7] * b + R[8] * c;
  }
  y[15] = R[0] * x[15];  // padded vector (x15,0,0): only row0 col0 survives
}

__global__ __launch_bounds__(64) void attn_kernel(const unsigned short* __restrict__ qkvh,
                                                  const float* __restrict__ Rbuf,
                                                  const float* __restrict__ pbw,
                                                  unsigned short* __restrict__ a0,
                                                  unsigned short* __restrict__ a1,
                                                  unsigned short* __restrict__ a2) {
  __shared__ float Klds[2][32][20];
  __shared__ float Vlds[2][32][20];
  const int axial = blockIdx.z;
  unsigned short* dstbuf = (axial == 0) ? a0 : ((axial == 1) ? a1 : a2);
  int seq = blockIdx.x, hp = blockIdx.y;
  int lane = threadIdx.x;
  int hh = lane >> 5;
  int head = hp * 2 + hh;
  int tok = lane & 31;
  int b = seq >> 10, rem = seq & 1023;
  int u = rem >> 5, v = rem & 31;
  int base, stride, comp;
  if (axial == 0) { base = (b << 15) + (u << 5) + v;  stride = 1024; comp = 2; }
  else if (axial == 1) { base = (b << 15) + (u << 10) + v; stride = 32; comp = 1; }
  else { base = (b << 15) + (u << 10) + (v << 5); stride = 1; comp = 0; }
  const float* Rp = Rbuf + (axial * 8 + head) * 18;
  float Rq[9], Rv[9];
  #pragma unroll
  for (int i = 0; i < 9; ++i) { Rq[i] = Rp[i]; Rv[i] = Rp[9 + i]; }
  size_t t_tok = (size_t)base + (size_t)tok * stride;
  const unsigned short* row = qkvh + (size_t)head * (NTOK * 48) + t_tok * 48;
  float xq[16], xk[16], xv[16];
  bf16x16_load(row, xq);
  bf16x16_load(row + 16, xk);
  bf16x16_load(row + 32, xv);
  float qr[16], kr[16], vr[16];
  rot16(Rq, xq, qr);
  rot16(Rq, xk, kr);
  rot16(Rv, xv, vr);
  #pragma unroll
  for (int j = 0; j < 16; ++j) { Klds[hh][tok][j] = kr[j]; Vlds[hh][tok][j] = vr[j]; }
  __syncthreads();
  float wb = pbw[comp];
  float s[32];
  #pragma unroll
  for (int k = 0; k < 32; ++k) {
    const float* kp = &Klds[hh][k][0];
    float dot = 0.f;
    #pragma unroll
    for (int j = 0; j < 16; ++j) dot += qr[j] * kp[j];
    float lin = -1.0f + (2.0f / 31.0f) * (float)k;
    s[k] = dot * 0.25f - lin * wb;
  }
  float m = s[0];
  #pragma unroll
  for (int k = 1; k < 32; ++k) m = fmaxf(m, s[k]);
  float sum = 0.f;
  #pragma unroll
  for (int k = 0; k < 32; ++k) { s[k] = expf(s[k] - m); sum += s[k]; }
  float inv = 1.0f / sum;
  float o[16];
  #pragma unroll
  for (int j = 0; j < 16; ++j) o[j] = 0.f;
  #pragma unroll
  for (int k = 0; k < 32; ++k) {
    float p = s[k];
    const float* vp = &Vlds[hh][k][0];
    #pragma unroll
    for (int j = 0; j < 16; ++j) o[j] += p * vp[j];
  }
  unsigned short* dst = dstbuf + t_tok * 128 + head * 16;
  #pragma unroll
  for (int j = 0; j < 16; ++j) dst[j] = f2bf(o[j] * inv);
}

// ---------------------------------------------------------------------------
extern "C" void kernel_launch(void* const* d_in, const int* in_sizes, int n_in,
                              void* d_out, int out_size, void* d_ws, size_t ws_size,
                              hipStream_t stream) {
  const float* x       = (const float*)d_in[0];
  const float* pos_emb = (const float*)d_in[1];
  const float* qkv_w   = (const float*)d_in[2];
  const float* qkv_b   = (const float*)d_in[3];
  const float* lp_w1   = (const float*)d_in[4];
  const float* lp_b1   = (const float*)d_in[5];
  const float* lp_w2   = (const float*)d_in[6];
  const float* lp_b2   = (const float*)d_in[7];
  const float* mod_w1  = (const float*)d_in[8];
  const float* mod_b1  = (const float*)d_in[9];
  const float* mod_w2  = (const float*)d_in[10];
  const float* mod_b2  = (const float*)d_in[11];
  // d_in[12] pa_w, d_in[13] pa_b: cancel in softmax (constant along key axis)
  const float* proj_w  = (const float*)d_in[14];
  const float* proj_b  = (const float*)d_in[15];
  const float* pbw     = (const float*)d_in[16];
  // d_in[17] pos_bias_b: cancels in softmax
  const float* Ad      = (const float*)d_in[18];
  const float* Ah      = (const float*)d_in[19];
  const float* Aw      = (const float*)d_in[20];
  const float* Rd      = (const float*)d_in[21];
  const float* Rh      = (const float*)d_in[22];
  const float* Rw      = (const float*)d_in[23];
  // d_in[24..26] t_d/t_h/t_w: cancel in rel (pairwise difference)

  float* ws = (float*)d_ws;
  float* R0     = ws + WS_R0;
  float* mpre   = ws + WS_MPRE;
  float* xtok   = ws + WS_XTOK;
  unsigned short* A0b    = (unsigned short*)(ws + WS_A0);
  unsigned short* A1b    = (unsigned short*)(ws + WS_A1);
  unsigned short* A2b    = (unsigned short*)(ws + WS_A2);
  unsigned short* inT    = (unsigned short*)(ws + WS_INT);
  unsigned short* qkvh   = (unsigned short*)(ws + WS_QKVH);
  unsigned short* convP  = (unsigned short*)(ws + WS_CONVP);
  unsigned short* qkvP   = (unsigned short*)(ws + WS_QKVP);
  unsigned short* WcP    = (unsigned short*)(ws + WS_WCP);
  unsigned short* modw2P = (unsigned short*)(ws + WS_MODW2P);
  unsigned short* projP  = (unsigned short*)(ws + WS_PROJP);
  float* bc     = ws + WS_BC;
  float* Rbuf   = ws + WS_RBUF;
  float* ps     = ws + WS_PS;
  float* pss    = ws + WS_PSS;
  float* mu1    = ws + WS_MU1;
  float* rs1    = ws + WS_RS1;
  float* mu2    = ws + WS_MU2;
  float* rs2    = ws + WS_RS2;
  unsigned short* xmodb = inT;  // x_mod bf16 reuses INT region (inT dead after conv)

  prep_r_kernel<<<1, 64, 0, stream>>>(Ad, Ah, Aw, Rd, Rh, Rw, Rbuf);
  prep_w_kernel<<<256, 256, 0, stream>>>(lp_w1, qkv_w, mod_w1, lp_w2, lp_b2, mod_b1,
                                         mod_w2, proj_w, convP, qkvP, WcP, modw2P, projP, bc);
  transpose_kernel<<<2048, 256, 0, stream>>>(x, pos_emb, xtok, inT);
  // lf = circular conv3x3x3(pos_emb), fused stats partials
  conv_mfma_kernel<<<512, 256, 0, stream>>>(inT, convP, lp_b1, R0, ps, pss);
  stats_final_kernel<<<1, 256, 0, stream>>>(ps, pss, mu1, rs1);
  // m_pre = gelu(inorm(lf)) @ Wc^T + bc, fused stats partials
  gemm_mfma_kernel<1, 0, 0, 1><<<dim3(1, 512), 256, 0, stream>>>(
      R0, WcP, bc, mpre, 128, mu1, rs1, nullptr, ps, pss);
  stats_final_kernel<<<1, 256, 0, stream>>>(ps, pss, mu2, rs2);
  // x_mod (bf16) = x * sigmoid(gelu(inorm(m_pre)) @ mod_w2^T + mod_b2)
  gemm_mfma_kernel<1, 0, 1, 0><<<dim3(1, 512), 256, 0, stream>>>(
      mpre, modw2P, mod_b2, xmodb, 128, mu2, rs2, xtok, nullptr, nullptr);
  // qkv (bf16, head-major) = x_mod @ qkv_w^T + qkv_b
  gemm_mfma_kernel<0, 1, 2, 0><<<dim3(3, 512), 256, 0, stream>>>(
      xmodb, qkvP, qkv_b, qkvh, 384, nullptr, nullptr, nullptr, nullptr, nullptr);
  // three axial attentions in one dispatch, separate bf16 outputs
  attn_kernel<<<dim3(2048, 4, 3), 64, 0, stream>>>(qkvh, Rbuf, pbw, A0b, A1b, A2b);
  // final projection of (A0+A1+A2) -> NCDHW output
  proj_mfma_kernel<<<512, 256, 0, stream>>>(A0b, A1b, A2b, projP, proj_b, (float*)d_out);
}

// Round 7
// 336.623 us; speedup vs baseline: 1.8188x; 1.4502x over previous
//
#include <hip/hip_runtime.h>
#include <cstdint>
#include <cstddef>

// ---------------------------------------------------------------------------
// Problem constants: B=2, C=128, D=H=W=32, nh=8, hd=16, L=32
// Tokens: t = b*32768 + d*1024 + h*32 + w   (65536 tokens, 128 channels)
// ---------------------------------------------------------------------------

#define NTOK 65536
#define SPAT 32768

// ws offsets (floats). Timeline:
//   transpose: writes XTOKB (bf16 x) + INT (bf16 pos_emb)      [disjoint]
//   conv:      reads INT, writes R0 (lf fp32) + stats
//   gemmWc:    reads R0, writes MPREB (bf16) + stats            (R0 dead after)
//   gemmGate:  reads MPREB+XTOKB, writes XMODB=INT              (MPREB dead after)
//   gemmQKV:   reads XMODB, writes QKVH (head-major bf16)
//   attn:      reads QKVH, writes A0,A1 (over dead R0), A2 (over dead MPREB)
//   proj:      reads A0+A1+A2 -> d_out
// SIZES: all bf16 token buffers are NTOK*128 ush = 4194304 floats (r6 bug: was 2M)
#define WS_R0     0ull          // 8388608 fp32 (lf)
#define WS_A0     0ull          // 4194304 (8388608 ush)
#define WS_A1     4194304ull    // 4194304
#define WS_MPREB  8388608ull    // 4194304 (8388608 ush)
#define WS_A2     8388608ull    // 4194304 (overlays dead MPREB)
#define WS_XTOKB  12582912ull   // 4194304 (8388608 ush)
#define WS_INT    16777216ull   // 4194304 (8388608 ush): pos_emb bf16 -> x_mod bf16
#define WS_QKVH   20971520ull   // 12582912 (25165824 ush) [h][t][48]
#define WS_CONVP  33554432ull   // 221184 (442368 ush) [tap][dx][ks][l4][co][8]
#define WS_QKVP   33775616ull   // 24576  (49152 ush)
#define WS_WCP    33800192ull   // 8192
#define WS_MODW2P 33808384ull   // 8192
#define WS_PROJP  33816576ull   // 8192
#define WS_BC     33824768ull   // 128
#define WS_RBUF   33824896ull   // 432
#define WS_PS     33825328ull   // 131072 (1024 blocks x 128)
#define WS_PSS    33956400ull   // 131072
#define WS_MU1    34087472ull   // 256
#define WS_RS1    34087728ull   // 256
#define WS_MU2    34087984ull   // 256
#define WS_RS2    34088240ull   // 256
// total 34088496 floats = 136.4 MB (<= 136.6 MB proven in r1/r2)

typedef __attribute__((ext_vector_type(8))) short short8;
typedef __attribute__((ext_vector_type(4))) float f32x4;

__device__ __forceinline__ float gelu_f(float x) {
  return 0.5f * x * (1.0f + erff(x * 0.70710678118654752f));
}
__device__ __forceinline__ float sigmoid_f(float x) {
  return 1.0f / (1.0f + expf(-x));
}
__device__ __forceinline__ unsigned short f2bf(float x) {  // RNE f32->bf16
  unsigned int u = __float_as_uint(x);
  unsigned int r = u + 0x7fffu + ((u >> 16) & 1u);
  return (unsigned short)(r >> 16);
}
__device__ __forceinline__ float bf2f(unsigned short u) {
  return __uint_as_float(((unsigned int)u) << 16);
}
__device__ __forceinline__ short8 pack_bf8(float4 v0, float4 v1) {
  short8 r;
  r[0] = (short)f2bf(v0.x); r[1] = (short)f2bf(v0.y);
  r[2] = (short)f2bf(v0.z); r[3] = (short)f2bf(v0.w);
  r[4] = (short)f2bf(v1.x); r[5] = (short)f2bf(v1.y);
  r[6] = (short)f2bf(v1.z); r[7] = (short)f2bf(v1.w);
  return r;
}
// 16 consecutive bf16 -> 16 fp32
__device__ __forceinline__ void bf16x16_load(const unsigned short* p, float* f) {
  const uint4 a = *(const uint4*)p;
  const uint4 b = *(const uint4*)(p + 8);
  const unsigned int w[8] = {a.x, a.y, a.z, a.w, b.x, b.y, b.z, b.w};
  #pragma unroll
  for (int i = 0; i < 8; ++i) {
    f[2 * i] = __uint_as_float(w[i] << 16);
    f[2 * i + 1] = __uint_as_float(w[i] & 0xffff0000u);
  }
}
// async global->LDS, 16B per lane (dest must be wave-uniform base + lane*16)
__device__ __forceinline__ void gload_lds16(const void* g, void* l) {
  __builtin_amdgcn_global_load_lds(
      (const __attribute__((address_space(1))) unsigned int*)g,
      (__attribute__((address_space(3))) unsigned int*)l, 16, 0, 0);
}
__device__ __forceinline__ float dot3(const float* a, const float* b) {
  return a[0] * b[0] + a[1] * b[1] + a[2] * b[2];
}
__device__ __forceinline__ void cross3(const float* a, const float* b, float* c) {
  c[0] = a[1] * b[2] - a[2] * b[1];
  c[1] = a[2] * b[0] - a[0] * b[2];
  c[2] = a[0] * b[1] - a[1] * b[0];
}

// exact port of _r6_to_matrix for one head (6 floats in, 9 out row-major)
__device__ void r6_to_matrix(const float* r6, float* R) {
  float v1[3] = {r6[0], r6[1], r6[2]};
  float n1 = sqrtf(dot3(v1, v1));
  float inv1 = 1.0f / (n1 + 1e-7f);
  v1[0] *= inv1; v1[1] *= inv1; v1[2] *= inv1;
  float v2[3] = {r6[3], r6[4], r6[5]};
  float d = dot3(v2, v1);
  v2[0] -= d * v1[0]; v2[1] -= d * v1[1]; v2[2] -= d * v1[2];
  float n2 = sqrtf(dot3(v2, v2));
  float inv2 = 1.0f / (n2 + 1e-7f);
  v2[0] *= inv2; v2[1] *= inv2; v2[2] *= inv2;
  float v3[3]; cross3(v1, v2, v3);
  float cx[3]; cross3(v2, v3, cx);
  float det = dot3(v1, cx);
  if (det < 0.0f) { v3[0] = -v3[0]; v3[1] = -v3[1]; v3[2] = -v3[2]; }
  R[0] = v1[0]; R[1] = v1[1]; R[2] = v1[2];
  R[3] = v2[0]; R[4] = v2[1]; R[5] = v2[2];
  R[6] = v3[0]; R[7] = v3[1]; R[8] = v3[2];
}

// exact port of _ensure_matrix for one head (9 in row-major, 9 out)
__device__ void ensure_matrix(const float* Rin, float* Ro) {
  float a[3] = {Rin[0] + 1e-6f, Rin[1] + 1e-6f, Rin[2] + 1e-6f};
  float na = fmaxf(sqrtf(dot3(a, a)), 1e-12f);
  float v1[3] = {a[0] / na, a[1] / na, a[2] / na};
  float b0[3] = {Rin[3], Rin[4], Rin[5]};
  float d = dot3(b0, v1);
  float bb[3] = {b0[0] - d * v1[0] + 1e-6f, b0[1] - d * v1[1] + 1e-6f, b0[2] - d * v1[2] + 1e-6f};
  float nb = fmaxf(sqrtf(dot3(bb, bb)), 1e-12f);
  float v2[3] = {bb[0] / nb, bb[1] / nb, bb[2] / nb};
  float v3[3]; cross3(v1, v2, v3);
  float cx[3]; cross3(v2, v3, cx);
  float det = dot3(v1, cx);
  if (det < 0.0f) { v3[0] = -v3[0]; v3[1] = -v3[1]; v3[2] = -v3[2]; }
  float Rn[9] = {v1[0], v1[1], v1[2], v2[0], v2[1], v2[2], v3[0], v3[1], v3[2]};
  float T1[9], T2[9];
  for (int i = 0; i < 3; ++i)
    for (int j = 0; j < 3; ++j) {
      float s = 0.f;
      for (int k = 0; k < 3; ++k) s += Rn[k * 3 + i] * Rn[k * 3 + j];
      T1[i * 3 + j] = s;
    }
  for (int i = 0; i < 3; ++i)
    for (int j = 0; j < 3; ++j) {
      float s = 0.f;
      for (int k = 0; k < 3; ++k) s += T1[i * 3 + k] * Rn[j * 3 + k];
      T2[i * 3 + j] = s;
    }
  for (int i = 0; i < 9; ++i) Ro[i] = 0.5f * (Rn[i] + T2[i]);
}

// ---------------------------------------------------------------------------
// K0: weight packs (+ rotation matrices in block 0)
//   convP: [tap][dx][ks][l4][co][8ci]  -> B-fragment loads 256B-coalesced
// ---------------------------------------------------------------------------
__global__ __launch_bounds__(256) void prep_w_kernel(
    const float* __restrict__ lp_w1, const float* __restrict__ qkv_w,
    const float* __restrict__ mod_w1, const float* __restrict__ lp_w2,
    const float* __restrict__ lp_b2, const float* __restrict__ mod_b1,
    const float* __restrict__ mod_w2, const float* __restrict__ proj_w,
    const float* __restrict__ Ad, const float* __restrict__ Ah,
    const float* __restrict__ Aw, const float* __restrict__ Rd,
    const float* __restrict__ Rh, const float* __restrict__ Rw,
    unsigned short* __restrict__ convP, unsigned short* __restrict__ qkvP,
    unsigned short* __restrict__ WcP, unsigned short* __restrict__ modw2P,
    unsigned short* __restrict__ projP, float* __restrict__ bc,
    float* __restrict__ Rbuf) {
  int gid = blockIdx.x * 256 + threadIdx.x;  // 65536 threads
  for (int f = gid; f < 442368; f += 65536) {
    // f = ((((tap*3+dx)*4+ks)*4+l4)*128+co)*8 + e ; ci = ks*32+l4*8+e
    int e = f & 7;
    int co = (f >> 3) & 127;
    int rest = f >> 10;
    int l4 = rest & 3;
    int ks = (rest >> 2) & 3;
    int dxt = rest >> 4;
    int dx = dxt % 3;
    int tap = dxt / 3;
    int dz = tap / 3, dy = tap % 3;
    int ci = ks * 32 + l4 * 8 + e;
    convP[f] = f2bf(lp_w1[(co * 128 + ci) * 27 + dz * 9 + dy * 3 + dx]);
  }
  if (gid < 49152) qkvP[gid] = f2bf(qkv_w[gid]);
  if (gid < 16384) {
    modw2P[gid] = f2bf(mod_w2[gid]);
    projP[gid] = f2bf(proj_w[gid]);
    int o = gid >> 7, i = gid & 127;
    float s = 0.f;
    for (int c = 0; c < 128; ++c) s += mod_w1[o * 128 + c] * lp_w2[c * 128 + i];
    WcP[gid] = f2bf(s);
  }
  if (gid < 128) {
    float s = 0.f;
    for (int c = 0; c < 128; ++c) s += mod_w1[gid * 128 + c] * lp_b2[c];
    bc[gid] = s + mod_b1[gid];
  }
  if (blockIdx.x == 0 && threadIdx.x >= 224 && threadIdx.x < 248) {
    int tid = threadIdx.x - 224;
    int ax = tid >> 3, h = tid & 7;
    const float* A = (ax == 0) ? Ad : ((ax == 1) ? Ah : Aw);
    const float* R = (ax == 0) ? Rd : ((ax == 1) ? Rh : Rw);
    float Rq[9], Rv[9];
    r6_to_matrix(A + h * 6, Rq);
    ensure_matrix(R + h * 9, Rv);
    float* dst = Rbuf + (ax * 8 + h) * 18;
    for (int i = 0; i < 9; ++i) { dst[i] = Rq[i]; dst[9 + i] = Rv[i]; }
  }
}

// ---------------------------------------------------------------------------
// K0c: merged transposes. Per (b,d,h) plane: x -> xtokb bf16, pos_emb -> inT bf16
// ---------------------------------------------------------------------------
__global__ __launch_bounds__(256) void transpose_kernel(const float* __restrict__ x,
                                                        const float* __restrict__ pe,
                                                        unsigned short* __restrict__ xtokb,
                                                        unsigned short* __restrict__ inT) {
  __shared__ float lds[32][132];
  int blk = blockIdx.x;  // b*1024 + d*32 + h
  int b = blk >> 10;
  int dh = blk & 1023;
  int tid = threadIdx.x;
  size_t planebase = ((size_t)b << 22) + ((size_t)dh << 5);
  size_t tb = ((size_t)blk) << 5;
  #pragma unroll
  for (int r = 0; r < 16; ++r) {
    int idx = r * 256 + tid;
    int ci = idx >> 5, w = idx & 31;
    lds[w][ci] = x[planebase + ((size_t)ci << 15) + w];
  }
  __syncthreads();
  #pragma unroll
  for (int r = 0; r < 16; ++r) {
    int idx = r * 256 + tid;
    int w = idx >> 7, ci = idx & 127;
    xtokb[(tb + w) * 128 + ci] = f2bf(lds[w][ci]);
  }
  __syncthreads();
  #pragma unroll
  for (int r = 0; r < 16; ++r) {
    int idx = r * 256 + tid;
    int ci = idx >> 5, w = idx & 31;
    lds[w][ci] = pe[planebase + ((size_t)ci << 15) + w];
  }
  __syncthreads();
  #pragma unroll
  for (int r = 0; r < 16; ++r) {
    int idx = r * 256 + tid;
    int w = idx >> 7, ci = idx & 127;
    inT[(tb + w) * 128 + ci] = f2bf(lds[w][ci]);
  }
}

// ---------------------------------------------------------------------------
// K1: 3x3x3 circular conv via bf16 MFMA, v4.
// Block: 64 tokens (2 h-rows x 32 w) x 128 co; 4 waves 2x2 (32tok x 64co each).
// Per-dz staging of a 4-row halo (32KB LDS) -> 288 MFMA/wave between barriers,
// 5 barriers total, 34KB LDS -> 4 blocks/CU. Fused inorm stats in epilogue.
// ---------------------------------------------------------------------------
__global__ __launch_bounds__(256) void conv_mfma_kernel(
    const unsigned short* __restrict__ inT, const unsigned short* __restrict__ Bp,
    const float* __restrict__ b1, float* __restrict__ out,
    float* __restrict__ ps, float* __restrict__ pss) {
  __shared__ unsigned short Als[16384];  // 32KB: 4 rows x 32 w x 128 ci, swizzled
  __shared__ float sumb[128][2];
  __shared__ float sqb[128][2];
  const int blk = blockIdx.x;             // 1024 blocks
  const int b = blk >> 9, d = (blk >> 4) & 31, hg = blk & 15;
  const int h0 = hg << 1;                 // 2 output h-rows
  const int tid = threadIdx.x;
  const int lane = tid & 63;
  const int wid = tid >> 6;
  const int wm = wid >> 1, wn = wid & 1;
  const int l15 = lane & 15, l4 = lane >> 4;

  f32x4 acc[2][4];
  #pragma unroll
  for (int mt = 0; mt < 2; ++mt)
    #pragma unroll
    for (int nt = 0; nt < 4; ++nt)
      #pragma unroll
      for (int r = 0; r < 4; ++r) acc[mt][nt][r] = 0.f;

  int mw[2], mhh[2];
  #pragma unroll
  for (int mt = 0; mt < 2; ++mt) {
    int m = wm * 32 + mt * 16 + l15;
    mhh[mt] = m >> 5;
    mw[mt] = m & 31;
  }
  const size_t tokbase = ((size_t)b << 15) + ((size_t)d << 10) + ((size_t)h0 << 5);

  // stage 4-row halo (h0-1 .. h0+2) of plane (d+dz-1) -> 32KB
  auto stage = [&](int dz) {
    const int zr = (d + dz + 31) & 31;
    #pragma unroll
    for (int p = 0; p < 8; ++p) {
      const int g = p * 256 + tid;        // 2048 chunks of 16B
      const int tok = g >> 4, gi = g & 15;
      const int r = tok >> 5, w = tok & 31;
      const int yr = (h0 + r + 31) & 31;
      const size_t srcbyte = ((((size_t)b << 15) + ((size_t)zr << 10) + ((size_t)yr << 5) + w) << 8)
                             + (size_t)((gi ^ (w & 7)) << 4);
      gload_lds16((const char*)inT + srcbyte, (char*)Als + (size_t)g * 16);
    }
  };

  auto compute = [&](int dz) {
    #pragma unroll
    for (int dy = 0; dy < 3; ++dy) {
      const int tap = dz * 3 + dy;
      #pragma unroll
      for (int dx = 0; dx < 3; ++dx) {
        int abase[2], asw[2];
        #pragma unroll
        for (int mt = 0; mt < 2; ++mt) {
          const int wsft = (mw[mt] + dx + 31) & 31;
          const int stok = (mhh[mt] + dy) * 32 + wsft;
          abase[mt] = stok * 256;
          asw[mt] = (wsft & 7) << 4;
        }
        #pragma unroll
        for (int ks = 0; ks < 4; ++ks) {
          const int k2 = (ks * 32 + l4 * 8) * 2;
          const int bbase = (((tap * 3 + dx) * 4 + ks) * 4 + l4) * 1024;
          short8 afr[2], bfr[4];
          #pragma unroll
          for (int nt = 0; nt < 4; ++nt) {
            const int co = wn * 64 + nt * 16 + l15;
            bfr[nt] = *(const short8*)(Bp + bbase + co * 8);
          }
          #pragma unroll
          for (int mt = 0; mt < 2; ++mt)
            afr[mt] = *(const short8*)((const char*)Als + abase[mt] + (k2 ^ asw[mt]));
          #pragma unroll
          for (int mt = 0; mt < 2; ++mt)
            #pragma unroll
            for (int nt = 0; nt < 4; ++nt)
              acc[mt][nt] = __builtin_amdgcn_mfma_f32_16x16x32_bf16(afr[mt], bfr[nt],
                                                                    acc[mt][nt], 0, 0, 0);
        }
      }
    }
  };

  for (int dz = 0; dz < 3; ++dz) {
    stage(dz);
    __syncthreads();   // stage complete (drains vmcnt)
    compute(dz);
    if (dz < 2) __syncthreads();  // all reads done before next stage overwrites
  }

  // epilogue: bias + store + fused stats partials
  #pragma unroll
  for (int nt = 0; nt < 4; ++nt) {
    const int co = wn * 64 + nt * 16 + l15;
    const float bias = b1[co];
    float s = 0.f, q = 0.f;
    #pragma unroll
    for (int mt = 0; mt < 2; ++mt) {
      #pragma unroll
      for (int r = 0; r < 4; ++r) {
        const int m = wm * 32 + mt * 16 + l4 * 4 + r;
        const float v = acc[mt][nt][r] + bias;
        out[(tokbase + m) * 128 + co] = v;
        s += v; q += v * v;
      }
    }
    s += __shfl_xor(s, 16); s += __shfl_xor(s, 32);
    q += __shfl_xor(q, 16); q += __shfl_xor(q, 32);
    if (l4 == 0) { sumb[co][wm] = s; sqb[co][wm] = q; }
  }
  __syncthreads();
  if (tid < 128) {
    ps[blk * 128 + tid] = sumb[tid][0] + sumb[tid][1];
    pss[blk * 128 + tid] = sqb[tid][0] + sqb[tid][1];
  }
}

// ---------------------------------------------------------------------------
// K2: stats finalize, parallel: one block per (b,c); nb partial blocks per batch
// ---------------------------------------------------------------------------
__global__ __launch_bounds__(64) void stats_final_kernel(
    const float* __restrict__ ps, const float* __restrict__ pss,
    float* __restrict__ mu, float* __restrict__ rs, int nb) {
  const int pair = blockIdx.x;  // b*128 + c
  const int b = pair >> 7, c = pair & 127;
  const int lane = threadIdx.x;
  float s = 0.f, ss = 0.f;
  for (int j = lane; j < nb; j += 64) {
    const int idx = ((b * nb + j) << 7) + c;
    s += ps[idx];
    ss += pss[idx];
  }
  #pragma unroll
  for (int o = 32; o > 0; o >>= 1) {
    s += __shfl_xor(s, o);
    ss += __shfl_xor(ss, o);
  }
  if (lane == 0) {
    float m = s * (1.0f / 32768.0f);
    float v = ss * (1.0f / 32768.0f) - m * m;
    mu[pair] = m;
    rs[pair] = rsqrtf(v + 1e-5f);
  }
}

// ---------------------------------------------------------------------------
// K3: 1x1 GEMM via bf16 MFMA, register-only.
// PRE: 0 none | 1 gelu(inorm)   AB16: A dtype (0 fp32, 1 bf16)
// POST: 0 fp32 [t][O] | 1 sigmoid*x -> bf16 [t][128] | 2 bf16 [t][O]
//       | 3 bf16 head-major qkv [h][t][48]
// STATS: fused per-block column sums -> ps/pss
// Block: 128 tokens x 128 o; 4 waves 2x2. grid (O/128, NTOK/128)
// ---------------------------------------------------------------------------
template <int PRE, int AB16, int POST, int STATS>
__global__ __launch_bounds__(256) void gemm_mfma_kernel(
    const void* __restrict__ Avoid, const unsigned short* __restrict__ Wp,
    const float* __restrict__ bias, void* __restrict__ Yvoid, int O,
    const float* __restrict__ mu, const float* __restrict__ rs,
    const unsigned short* __restrict__ xtb, float* __restrict__ ps,
    float* __restrict__ pss) {
  __shared__ float sumb[128][2];
  __shared__ float sqb[128][2];
  const int tid = threadIdx.x;
  const int lane = tid & 63, wid = tid >> 6;
  const int wm = wid >> 1, wn = wid & 1;
  const int l15 = lane & 15, l4 = lane >> 4;
  const int og = blockIdx.x * 128;
  const int t0 = blockIdx.y * 128;
  const int bidx = t0 >> 15;
  const float* Af = (const float*)Avoid;
  const unsigned short* Ab = (const unsigned short*)Avoid;
  float* Yf = (float*)Yvoid;
  unsigned short* Yb = (unsigned short*)Yvoid;

  f32x4 acc[4][4];
  #pragma unroll
  for (int mt = 0; mt < 4; ++mt)
    #pragma unroll
    for (int nt = 0; nt < 4; ++nt)
      #pragma unroll
      for (int r = 0; r < 4; ++r) acc[mt][nt][r] = 0.f;

  #pragma unroll
  for (int ks = 0; ks < 4; ++ks) {
    const int kb = ks * 32 + l4 * 8;
    short8 a[4], bfr[4];
    float4 m0, m1, r0, r1;
    if constexpr (PRE == 1) {
      m0 = *(const float4*)(mu + bidx * 128 + kb);
      m1 = *(const float4*)(mu + bidx * 128 + kb + 4);
      r0 = *(const float4*)(rs + bidx * 128 + kb);
      r1 = *(const float4*)(rs + bidx * 128 + kb + 4);
    }
    #pragma unroll
    for (int mt = 0; mt < 4; ++mt) {
      const int tok = t0 + wm * 64 + mt * 16 + l15;
      float v[16];
      bool have = false;
      if constexpr (AB16 == 1) {
        if constexpr (PRE == 1) {
          bf16x16_load(Ab + (size_t)tok * 128 + kb, v);
          have = true;
        } else {
          a[mt] = *(const short8*)(Ab + (size_t)tok * 128 + kb);
        }
      } else {
        const float* ap = Af + (size_t)tok * 128 + kb;
        float4 v0 = *(const float4*)ap;
        float4 v1 = *(const float4*)(ap + 4);
        v[0] = v0.x; v[1] = v0.y; v[2] = v0.z; v[3] = v0.w;
        v[4] = v1.x; v[5] = v1.y; v[6] = v1.z; v[7] = v1.w;
        have = true;
      }
      if (have) {
        if constexpr (PRE == 1) {
          const float mm[8] = {m0.x, m0.y, m0.z, m0.w, m1.x, m1.y, m1.z, m1.w};
          const float rr[8] = {r0.x, r0.y, r0.z, r0.w, r1.x, r1.y, r1.z, r1.w};
          #pragma unroll
          for (int j = 0; j < 8; ++j) v[j] = gelu_f((v[j] - mm[j]) * rr[j]);
        }
        short8 t;
        #pragma unroll
        for (int j = 0; j < 8; ++j) t[j] = (short)f2bf(v[j]);
        a[mt] = t;
      }
    }
    #pragma unroll
    for (int nt = 0; nt < 4; ++nt) {
      const int o = og + wn * 64 + nt * 16 + l15;
      bfr[nt] = *(const short8*)(Wp + (size_t)o * 128 + kb);
    }
    #pragma unroll
    for (int mt = 0; mt < 4; ++mt)
      #pragma unroll
      for (int nt = 0; nt < 4; ++nt)
        acc[mt][nt] = __builtin_amdgcn_mfma_f32_16x16x32_bf16(a[mt], bfr[nt], acc[mt][nt], 0, 0, 0);
  }

  #pragma unroll
  for (int nt = 0; nt < 4; ++nt) {
    const int o = og + wn * 64 + nt * 16 + l15;
    const float bb = bias[o];
    float s = 0.f, q = 0.f;
    #pragma unroll
    for (int mt = 0; mt < 4; ++mt) {
      #pragma unroll
      for (int r = 0; r < 4; ++r) {
        const int t = t0 + wm * 64 + mt * 16 + l4 * 4 + r;
        const float v = acc[mt][nt][r] + bb;
        if constexpr (POST == 0) {
          Yf[(size_t)t * O + o] = v;
        } else if constexpr (POST == 1) {
          Yb[(size_t)t * 128 + o] = f2bf(sigmoid_f(v) * bf2f(xtb[(size_t)t * 128 + o]));
        } else if constexpr (POST == 2) {
          Yb[(size_t)t * O + o] = f2bf(v);
        } else {
          // head-major qkv: [h][t][48] with q|k|v 16-ch sections
          const int which = o >> 7, hsub = (o & 127) >> 4, ch = o & 15;
          Yb[((size_t)hsub * NTOK + t) * 48 + which * 16 + ch] = f2bf(v);
        }
        if constexpr (STATS) { s += v; q += v * v; }
      }
    }
    if constexpr (STATS) {
      s += __shfl_xor(s, 16); s += __shfl_xor(s, 32);
      q += __shfl_xor(q, 16); q += __shfl_xor(q, 32);
      if (l4 == 0) { sumb[o - og][wm] = s; sqb[o - og][wm] = q; }
    }
  }
  if constexpr (STATS) {
    __syncthreads();
    if (tid < 128) {
      ps[blockIdx.y * 128 + tid] = sumb[tid][0] + sumb[tid][1];
      pss[blockIdx.y * 128 + tid] = sqb[tid][0] + sqb[tid][1];
    }
  }
}

// ---------------------------------------------------------------------------
// K6: final projection over A0+A1+A2 (bf16), swapped orientation -> NCDHW
// ---------------------------------------------------------------------------
__global__ __launch_bounds__(256) void proj_mfma_kernel(
    const unsigned short* __restrict__ A0b, const unsigned short* __restrict__ A1b,
    const unsigned short* __restrict__ A2b, const unsigned short* __restrict__ Wp,
    const float* __restrict__ bias, float* __restrict__ out) {
  const int tid = threadIdx.x;
  const int lane = tid & 63, wid = tid >> 6;
  const int wm = wid >> 1, wn = wid & 1;  // wm: o half, wn: token half
  const int l15 = lane & 15, l4 = lane >> 4;
  const int t0 = blockIdx.x * 128;

  f32x4 acc[4][4];
  #pragma unroll
  for (int mt = 0; mt < 4; ++mt)
    #pragma unroll
    for (int nt = 0; nt < 4; ++nt)
      #pragma unroll
      for (int r = 0; r < 4; ++r) acc[mt][nt][r] = 0.f;

  #pragma unroll
  for (int ks = 0; ks < 4; ++ks) {
    const int kb = ks * 32 + l4 * 8;
    short8 a[4], bfr[4];
    #pragma unroll
    for (int mt = 0; mt < 4; ++mt) {
      const int o = wm * 64 + mt * 16 + l15;
      a[mt] = *(const short8*)(Wp + (size_t)o * 128 + kb);
    }
    #pragma unroll
    for (int nt = 0; nt < 4; ++nt) {
      const int tok = t0 + wn * 64 + nt * 16 + l15;
      const size_t off = (size_t)tok * 128 + kb;
      short8 s0 = *(const short8*)(A0b + off);
      short8 s1 = *(const short8*)(A1b + off);
      short8 s2 = *(const short8*)(A2b + off);
      short8 r;
      #pragma unroll
      for (int i = 0; i < 8; ++i) {
        float f = bf2f((unsigned short)s0[i]) + bf2f((unsigned short)s1[i]) +
                  bf2f((unsigned short)s2[i]);
        r[i] = (short)f2bf(f);
      }
      bfr[nt] = r;
    }
    #pragma unroll
    for (int mt = 0; mt < 4; ++mt)
      #pragma unroll
      for (int nt = 0; nt < 4; ++nt)
        acc[mt][nt] = __builtin_amdgcn_mfma_f32_16x16x32_bf16(a[mt], bfr[nt], acc[mt][nt], 0, 0, 0);
  }

  #pragma unroll
  for (int nt = 0; nt < 4; ++nt) {
    const int tok = t0 + wn * 64 + nt * 16 + l15;
    const int dhw = tok & 32767, bB = tok >> 15;
    #pragma unroll
    for (int mt = 0; mt < 4; ++mt) {
      #pragma unroll
      for (int r = 0; r < 4; ++r) {
        const int o = wm * 64 + mt * 16 + l4 * 4 + r;
        out[((size_t)(bB * 128 + o) << 15) + dhw] = acc[mt][nt][r] + bias[o];
      }
    }
  }
}

// ---------------------------------------------------------------------------
// K7: axial attention, all 3 axials in one dispatch (blockIdx.z = axial).
// qkv head-major bf16 [h][t][48]; per-axial bf16 output buffers (no RMW).
// Effective logit: q_r.k_r * 0.25 - lin[k] * pos_bias_w[comp]
// ---------------------------------------------------------------------------
__device__ __forceinline__ void rot16(const float* R, const float* x, float* y) {
  #pragma unroll
  for (int g = 0; g < 5; ++g) {
    float a = x[3 * g], b = x[3 * g + 1], c = x[3 * g + 2];
    y[3 * g + 0] = R[0] * a + R[1] * b + R[2] * c;
    y[3 * g + 1] = R[3] * a + R[4] * b + R[5] * c;
    y[3 * g + 2] = R[6] * a + R[7] * b + R[8] * c;
  }
  y[15] = R[0] * x[15];  // padded vector (x15,0,0): only row0 col0 survives
}

__global__ __launch_bounds__(64) void attn_kernel(const unsigned short* __restrict__ qkvh,
                                                  const float* __restrict__ Rbuf,
                                                  const float* __restrict__ pbw,
                                                  unsigned short* __restrict__ a0,
                                                  unsigned short* __restrict__ a1,
                                                  unsigned short* __restrict__ a2) {
  __shared__ float Klds[2][32][20];
  __shared__ float Vlds[2][32][20];
  const int axial = blockIdx.z;
  unsigned short* dstbuf = (axial == 0) ? a0 : ((axial == 1) ? a1 : a2);
  int seq = blockIdx.x, hp = blockIdx.y;
  int lane = threadIdx.x;
  int hh = lane >> 5;
  int head = hp * 2 + hh;
  int tok = lane & 31;
  int b = seq >> 10, rem = seq & 1023;
  int u = rem >> 5, v = rem & 31;
  int base, stride, comp;
  if (axial == 0) { base = (b << 15) + (u << 5) + v;  stride = 1024; comp = 2; }
  else if (axial == 1) { base = (b << 15) + (u << 10) + v; stride = 32; comp = 1; }
  else { base = (b << 15) + (u << 10) + (v << 5); stride = 1; comp = 0; }
  const float* Rp = Rbuf + (axial * 8 + head) * 18;
  float Rq[9], Rv[9];
  #pragma unroll
  for (int i = 0; i < 9; ++i) { Rq[i] = Rp[i]; Rv[i] = Rp[9 + i]; }
  size_t t_tok = (size_t)base + (size_t)tok * stride;
  const unsigned short* row = qkvh + (size_t)head * (NTOK * 48) + t_tok * 48;
  float xq[16], xk[16], xv[16];
  bf16x16_load(row, xq);
  bf16x16_load(row + 16, xk);
  bf16x16_load(row + 32, xv);
  float qr[16], kr[16], vr[16];
  rot16(Rq, xq, qr);
  rot16(Rq, xk, kr);
  rot16(Rv, xv, vr);
  #pragma unroll
  for (int j = 0; j < 16; ++j) { Klds[hh][tok][j] = kr[j]; Vlds[hh][tok][j] = vr[j]; }
  __syncthreads();
  float wb = pbw[comp];
  float s[32];
  #pragma unroll
  for (int k = 0; k < 32; ++k) {
    const float* kp = &Klds[hh][k][0];
    float dot = 0.f;
    #pragma unroll
    for (int j = 0; j < 16; ++j) dot += qr[j] * kp[j];
    float lin = -1.0f + (2.0f / 31.0f) * (float)k;
    s[k] = dot * 0.25f - lin * wb;
  }
  float m = s[0];
  #pragma unroll
  for (int k = 1; k < 32; ++k) m = fmaxf(m, s[k]);
  float sum = 0.f;
  #pragma unroll
  for (int k = 0; k < 32; ++k) { s[k] = expf(s[k] - m); sum += s[k]; }
  float inv = 1.0f / sum;
  float o[16];
  #pragma unroll
  for (int j = 0; j < 16; ++j) o[j] = 0.f;
  #pragma unroll
  for (int k = 0; k < 32; ++k) {
    float p = s[k];
    const float* vp = &Vlds[hh][k][0];
    #pragma unroll
    for (int j = 0; j < 16; ++j) o[j] += p * vp[j];
  }
  unsigned short* dst = dstbuf + t_tok * 128 + head * 16;
  #pragma unroll
  for (int j = 0; j < 16; ++j) dst[j] = f2bf(o[j] * inv);
}

// ---------------------------------------------------------------------------
extern "C" void kernel_launch(void* const* d_in, const int* in_sizes, int n_in,
                              void* d_out, int out_size, void* d_ws, size_t ws_size,
                              hipStream_t stream) {
  const float* x       = (const float*)d_in[0];
  const float* pos_emb = (const float*)d_in[1];
  const float* qkv_w   = (const float*)d_in[2];
  const float* qkv_b   = (const float*)d_in[3];
  const float* lp_w1   = (const float*)d_in[4];
  const float* lp_b1   = (const float*)d_in[5];
  const float* lp_w2   = (const float*)d_in[6];
  const float* lp_b2   = (const float*)d_in[7];
  const float* mod_w1  = (const float*)d_in[8];
  const float* mod_b1  = (const float*)d_in[9];
  const float* mod_w2  = (const float*)d_in[10];
  const float* mod_b2  = (const float*)d_in[11];
  // d_in[12] pa_w, d_in[13] pa_b: cancel in softmax (constant along key axis)
  const float* proj_w  = (const float*)d_in[14];
  const float* proj_b  = (const float*)d_in[15];
  const float* pbw     = (const float*)d_in[16];
  // d_in[17] pos_bias_b: cancels in softmax
  const float* Ad      = (const float*)d_in[18];
  const float* Ah      = (const float*)d_in[19];
  const float* Aw      = (const float*)d_in[20];
  const float* Rd      = (const float*)d_in[21];
  const float* Rh      = (const float*)d_in[22];
  const float* Rw      = (const float*)d_in[23];
  // d_in[24..26] t_d/t_h/t_w: cancel in rel (pairwise difference)

  float* ws = (float*)d_ws;
  float* R0     = ws + WS_R0;
  unsigned short* A0b    = (unsigned short*)(ws + WS_A0);
  unsigned short* A1b    = (unsigned short*)(ws + WS_A1);
  unsigned short* A2b    = (unsigned short*)(ws + WS_A2);
  unsigned short* mpreb  = (unsigned short*)(ws + WS_MPREB);
  unsigned short* xtokb  = (unsigned short*)(ws + WS_XTOKB);
  unsigned short* inT    = (unsigned short*)(ws + WS_INT);
  unsigned short* qkvh   = (unsigned short*)(ws + WS_QKVH);
  unsigned short* convP  = (unsigned short*)(ws + WS_CONVP);
  unsigned short* qkvP   = (unsigned short*)(ws + WS_QKVP);
  unsigned short* WcP    = (unsigned short*)(ws + WS_WCP);
  unsigned short* modw2P = (unsigned short*)(ws + WS_MODW2P);
  unsigned short* projP  = (unsigned short*)(ws + WS_PROJP);
  float* bc     = ws + WS_BC;
  float* Rbuf   = ws + WS_RBUF;
  float* ps     = ws + WS_PS;
  float* pss    = ws + WS_PSS;
  float* mu1    = ws + WS_MU1;
  float* rs1    = ws + WS_RS1;
  float* mu2    = ws + WS_MU2;
  float* rs2    = ws + WS_RS2;
  unsigned short* xmodb = inT;  // x_mod bf16 reuses INT region (inT dead after conv)

  prep_w_kernel<<<256, 256, 0, stream>>>(lp_w1, qkv_w, mod_w1, lp_w2, lp_b2, mod_b1,
                                         mod_w2, proj_w, Ad, Ah, Aw, Rd, Rh, Rw,
                                         convP, qkvP, WcP, modw2P, projP, bc, Rbuf);
  transpose_kernel<<<2048, 256, 0, stream>>>(x, pos_emb, xtokb, inT);
  // lf = circular conv3x3x3(pos_emb), fused stats partials (1024 blocks)
  conv_mfma_kernel<<<1024, 256, 0, stream>>>(inT, convP, lp_b1, R0, ps, pss);
  stats_final_kernel<<<256, 64, 0, stream>>>(ps, pss, mu1, rs1, 512);
  // m_pre (bf16) = gelu(inorm(lf)) @ Wc^T + bc, fused stats partials
  gemm_mfma_kernel<1, 0, 2, 1><<<dim3(1, 512), 256, 0, stream>>>(
      R0, WcP, bc, mpreb, 128, mu1, rs1, nullptr, ps, pss);
  stats_final_kernel<<<256, 64, 0, stream>>>(ps, pss, mu2, rs2, 256);
  // x_mod (bf16) = x * sigmoid(gelu(inorm(m_pre)) @ mod_w2^T + mod_b2)
  gemm_mfma_kernel<1, 1, 1, 0><<<dim3(1, 512), 256, 0, stream>>>(
      mpreb, modw2P, mod_b2, xmodb, 128, mu2, rs2, xtokb, nullptr, nullptr);
  // qkv (bf16, head-major) = x_mod @ qkv_w^T + qkv_b
  gemm_mfma_kernel<0, 1, 3, 0><<<dim3(3, 512), 256, 0, stream>>>(
      xmodb, qkvP, qkv_b, qkvh, 384, nullptr, nullptr, nullptr, nullptr, nullptr);
  // three axial attentions in one dispatch, separate bf16 outputs
  attn_kernel<<<dim3(2048, 4, 3), 64, 0, stream>>>(qkvh, Rbuf, pbw, A0b, A1b, A2b);
  // final projection of (A0+A1+A2) -> NCDHW output
  proj_mfma_kernel<<<512, 256, 0, stream>>>(A0b, A1b, A2b, projP, proj_b, (float*)d_out);
}

// Round 8
// 306.417 us; speedup vs baseline: 1.9981x; 1.0986x over previous
//
#include <hip/hip_runtime.h>
#include <cstdint>
#include <cstddef>

// ---------------------------------------------------------------------------
// Problem constants: B=2, C=128, D=H=W=32, nh=8, hd=16, L=32
// Tokens: t = b*32768 + d*1024 + h*32 + w   (65536 tokens, 128 channels)
// ---------------------------------------------------------------------------

#define NTOK 65536
#define SPAT 32768

// ws offsets (floats). Same proven map as r7 (136.4 MB).
#define WS_R0     0ull          // 8388608 fp32 (lf)
#define WS_A0     0ull          // 4194304 (8388608 ush)
#define WS_A1     4194304ull    // 4194304
#define WS_MPREB  8388608ull    // 4194304 (8388608 ush)
#define WS_A2     8388608ull    // 4194304 (overlays dead MPREB)
#define WS_XTOKB  12582912ull   // 4194304 (8388608 ush)
#define WS_INT    16777216ull   // 4194304 (8388608 ush): pos_emb bf16 -> x_mod bf16
#define WS_QKVH   20971520ull   // 12582912 (25165824 ush) [h][t][48]
#define WS_CONVP  33554432ull   // 221184 (442368 ush) [tap][dx][ks][l4][co][8]
#define WS_QKVP   33775616ull   // 24576  (49152 ush)
#define WS_WCP    33800192ull   // 8192
#define WS_MODW2P 33808384ull   // 8192
#define WS_PROJP  33816576ull   // 8192
#define WS_BC     33824768ull   // 128
#define WS_RBUF   33824896ull   // 432
#define WS_PS     33825328ull   // 131072 (1024 blocks x 128)
#define WS_PSS    33956400ull   // 131072
#define WS_MU1    34087472ull   // 256
#define WS_RS1    34087728ull   // 256
#define WS_MU2    34087984ull   // 256
#define WS_RS2    34088240ull   // 256
// total 34088496 floats = 136.4 MB

typedef __attribute__((ext_vector_type(8))) short short8;
typedef __attribute__((ext_vector_type(4))) float f32x4;
typedef __attribute__((ext_vector_type(16))) float f32x16;

__device__ __forceinline__ float gelu_f(float x) {
  return 0.5f * x * (1.0f + erff(x * 0.70710678118654752f));
}
__device__ __forceinline__ float sigmoid_f(float x) {
  return 1.0f / (1.0f + expf(-x));
}
__device__ __forceinline__ unsigned short f2bf(float x) {  // RNE f32->bf16
  unsigned int u = __float_as_uint(x);
  unsigned int r = u + 0x7fffu + ((u >> 16) & 1u);
  return (unsigned short)(r >> 16);
}
__device__ __forceinline__ float bf2f(unsigned short u) {
  return __uint_as_float(((unsigned int)u) << 16);
}
// 16 consecutive bf16 -> 16 fp32
__device__ __forceinline__ void bf16x16_load(const unsigned short* p, float* f) {
  const uint4 a = *(const uint4*)p;
  const uint4 b = *(const uint4*)(p + 8);
  const unsigned int w[8] = {a.x, a.y, a.z, a.w, b.x, b.y, b.z, b.w};
  #pragma unroll
  for (int i = 0; i < 8; ++i) {
    f[2 * i] = __uint_as_float(w[i] << 16);
    f[2 * i + 1] = __uint_as_float(w[i] & 0xffff0000u);
  }
}
// async global->LDS, 16B per lane (dest must be wave-uniform base + lane*16)
__device__ __forceinline__ void gload_lds16(const void* g, void* l) {
  __builtin_amdgcn_global_load_lds(
      (const __attribute__((address_space(1))) unsigned int*)g,
      (__attribute__((address_space(3))) unsigned int*)l, 16, 0, 0);
}
__device__ __forceinline__ float dot3(const float* a, const float* b) {
  return a[0] * b[0] + a[1] * b[1] + a[2] * b[2];
}
__device__ __forceinline__ void cross3(const float* a, const float* b, float* c) {
  c[0] = a[1] * b[2] - a[2] * b[1];
  c[1] = a[2] * b[0] - a[0] * b[2];
  c[2] = a[0] * b[1] - a[1] * b[0];
}

// exact port of _r6_to_matrix for one head (6 floats in, 9 out row-major)
__device__ void r6_to_matrix(const float* r6, float* R) {
  float v1[3] = {r6[0], r6[1], r6[2]};
  float n1 = sqrtf(dot3(v1, v1));
  float inv1 = 1.0f / (n1 + 1e-7f);
  v1[0] *= inv1; v1[1] *= inv1; v1[2] *= inv1;
  float v2[3] = {r6[3], r6[4], r6[5]};
  float d = dot3(v2, v1);
  v2[0] -= d * v1[0]; v2[1] -= d * v1[1]; v2[2] -= d * v1[2];
  float n2 = sqrtf(dot3(v2, v2));
  float inv2 = 1.0f / (n2 + 1e-7f);
  v2[0] *= inv2; v2[1] *= inv2; v2[2] *= inv2;
  float v3[3]; cross3(v1, v2, v3);
  float cx[3]; cross3(v2, v3, cx);
  float det = dot3(v1, cx);
  if (det < 0.0f) { v3[0] = -v3[0]; v3[1] = -v3[1]; v3[2] = -v3[2]; }
  R[0] = v1[0]; R[1] = v1[1]; R[2] = v1[2];
  R[3] = v2[0]; R[4] = v2[1]; R[5] = v2[2];
  R[6] = v3[0]; R[7] = v3[1]; R[8] = v3[2];
}

// exact port of _ensure_matrix for one head (9 in row-major, 9 out)
__device__ void ensure_matrix(const float* Rin, float* Ro) {
  float a[3] = {Rin[0] + 1e-6f, Rin[1] + 1e-6f, Rin[2] + 1e-6f};
  float na = fmaxf(sqrtf(dot3(a, a)), 1e-12f);
  float v1[3] = {a[0] / na, a[1] / na, a[2] / na};
  float b0[3] = {Rin[3], Rin[4], Rin[5]};
  float d = dot3(b0, v1);
  float bb[3] = {b0[0] - d * v1[0] + 1e-6f, b0[1] - d * v1[1] + 1e-6f, b0[2] - d * v1[2] + 1e-6f};
  float nb = fmaxf(sqrtf(dot3(bb, bb)), 1e-12f);
  float v2[3] = {bb[0] / nb, bb[1] / nb, bb[2] / nb};
  float v3[3]; cross3(v1, v2, v3);
  float cx[3]; cross3(v2, v3, cx);
  float det = dot3(v1, cx);
  if (det < 0.0f) { v3[0] = -v3[0]; v3[1] = -v3[1]; v3[2] = -v3[2]; }
  float Rn[9] = {v1[0], v1[1], v1[2], v2[0], v2[1], v2[2], v3[0], v3[1], v3[2]};
  float T1[9], T2[9];
  for (int i = 0; i < 3; ++i)
    for (int j = 0; j < 3; ++j) {
      float s = 0.f;
      for (int k = 0; k < 3; ++k) s += Rn[k * 3 + i] * Rn[k * 3 + j];
      T1[i * 3 + j] = s;
    }
  for (int i = 0; i < 3; ++i)
    for (int j = 0; j < 3; ++j) {
      float s = 0.f;
      for (int k = 0; k < 3; ++k) s += T1[i * 3 + k] * Rn[j * 3 + k];
      T2[i * 3 + j] = s;
    }
  for (int i = 0; i < 9; ++i) Ro[i] = 0.5f * (Rn[i] + T2[i]);
}

// y = R_eff x for hd=16 (5 full 3x3 groups + scalar R00 on ch15)
__device__ __forceinline__ void rot16(const float* R, const float* x, float* y) {
  #pragma unroll
  for (int g = 0; g < 5; ++g) {
    float a = x[3 * g], b = x[3 * g + 1], c = x[3 * g + 2];
    y[3 * g + 0] = R[0] * a + R[1] * b + R[2] * c;
    y[3 * g + 1] = R[3] * a + R[4] * b + R[5] * c;
    y[3 * g + 2] = R[6] * a + R[7] * b + R[8] * c;
  }
  y[15] = R[0] * x[15];
}

// ---------------------------------------------------------------------------
// K0: weight packs (+ rotation matrices in block 0)
// ---------------------------------------------------------------------------
__global__ __launch_bounds__(256) void prep_w_kernel(
    const float* __restrict__ lp_w1, const float* __restrict__ qkv_w,
    const float* __restrict__ mod_w1, const float* __restrict__ lp_w2,
    const float* __restrict__ lp_b2, const float* __restrict__ mod_b1,
    const float* __restrict__ mod_w2, const float* __restrict__ proj_w,
    const float* __restrict__ Ad, const float* __restrict__ Ah,
    const float* __restrict__ Aw, const float* __restrict__ Rd,
    const float* __restrict__ Rh, const float* __restrict__ Rw,
    unsigned short* __restrict__ convP, unsigned short* __restrict__ qkvP,
    unsigned short* __restrict__ WcP, unsigned short* __restrict__ modw2P,
    unsigned short* __restrict__ projP, float* __restrict__ bc,
    float* __restrict__ Rbuf) {
  int gid = blockIdx.x * 256 + threadIdx.x;  // 65536 threads
  for (int f = gid; f < 442368; f += 65536) {
    int e = f & 7;
    int co = (f >> 3) & 127;
    int rest = f >> 10;
    int l4 = rest & 3;
    int ks = (rest >> 2) & 3;
    int dxt = rest >> 4;
    int dx = dxt % 3;
    int tap = dxt / 3;
    int dz = tap / 3, dy = tap % 3;
    int ci = ks * 32 + l4 * 8 + e;
    convP[f] = f2bf(lp_w1[(co * 128 + ci) * 27 + dz * 9 + dy * 3 + dx]);
  }
  if (gid < 49152) qkvP[gid] = f2bf(qkv_w[gid]);
  if (gid < 16384) {
    modw2P[gid] = f2bf(mod_w2[gid]);
    projP[gid] = f2bf(proj_w[gid]);
    int o = gid >> 7, i = gid & 127;
    float s = 0.f;
    for (int c = 0; c < 128; ++c) s += mod_w1[o * 128 + c] * lp_w2[c * 128 + i];
    WcP[gid] = f2bf(s);
  }
  if (gid < 128) {
    float s = 0.f;
    for (int c = 0; c < 128; ++c) s += mod_w1[gid * 128 + c] * lp_b2[c];
    bc[gid] = s + mod_b1[gid];
  }
  if (blockIdx.x == 0 && threadIdx.x >= 224 && threadIdx.x < 248) {
    int tid = threadIdx.x - 224;
    int ax = tid >> 3, h = tid & 7;
    const float* A = (ax == 0) ? Ad : ((ax == 1) ? Ah : Aw);
    const float* R = (ax == 0) ? Rd : ((ax == 1) ? Rh : Rw);
    float Rq[9], Rv[9];
    r6_to_matrix(A + h * 6, Rq);
    ensure_matrix(R + h * 9, Rv);
    float* dst = Rbuf + (ax * 8 + h) * 18;
    for (int i = 0; i < 9; ++i) { dst[i] = Rq[i]; dst[9 + i] = Rv[i]; }
  }
}

// ---------------------------------------------------------------------------
// K0c: merged transposes. Per (b,d,h) plane: x -> xtokb bf16, pos_emb -> inT bf16
// ---------------------------------------------------------------------------
__global__ __launch_bounds__(256) void transpose_kernel(const float* __restrict__ x,
                                                        const float* __restrict__ pe,
                                                        unsigned short* __restrict__ xtokb,
                                                        unsigned short* __restrict__ inT) {
  __shared__ float lds[32][132];
  int blk = blockIdx.x;  // b*1024 + d*32 + h
  int b = blk >> 10;
  int dh = blk & 1023;
  int tid = threadIdx.x;
  size_t planebase = ((size_t)b << 22) + ((size_t)dh << 5);
  size_t tb = ((size_t)blk) << 5;
  #pragma unroll
  for (int r = 0; r < 16; ++r) {
    int idx = r * 256 + tid;
    int ci = idx >> 5, w = idx & 31;
    lds[w][ci] = x[planebase + ((size_t)ci << 15) + w];
  }
  __syncthreads();
  #pragma unroll
  for (int r = 0; r < 16; ++r) {
    int idx = r * 256 + tid;
    int w = idx >> 7, ci = idx & 127;
    xtokb[(tb + w) * 128 + ci] = f2bf(lds[w][ci]);
  }
  __syncthreads();
  #pragma unroll
  for (int r = 0; r < 16; ++r) {
    int idx = r * 256 + tid;
    int ci = idx >> 5, w = idx & 31;
    lds[w][ci] = pe[planebase + ((size_t)ci << 15) + w];
  }
  __syncthreads();
  #pragma unroll
  for (int r = 0; r < 16; ++r) {
    int idx = r * 256 + tid;
    int w = idx >> 7, ci = idx & 127;
    inT[(tb + w) * 128 + ci] = f2bf(lds[w][ci]);
  }
}

// ---------------------------------------------------------------------------
// K1: 3x3x3 circular conv via bf16 MFMA, v4 (r7 proven).
// ---------------------------------------------------------------------------
__global__ __launch_bounds__(256) void conv_mfma_kernel(
    const unsigned short* __restrict__ inT, const unsigned short* __restrict__ Bp,
    const float* __restrict__ b1, float* __restrict__ out,
    float* __restrict__ ps, float* __restrict__ pss) {
  __shared__ unsigned short Als[16384];  // 32KB: 4 rows x 32 w x 128 ci, swizzled
  __shared__ float sumb[128][2];
  __shared__ float sqb[128][2];
  const int blk = blockIdx.x;             // 1024 blocks
  const int b = blk >> 9, d = (blk >> 4) & 31, hg = blk & 15;
  const int h0 = hg << 1;
  const int tid = threadIdx.x;
  const int lane = tid & 63;
  const int wid = tid >> 6;
  const int wm = wid >> 1, wn = wid & 1;
  const int l15 = lane & 15, l4 = lane >> 4;

  f32x4 acc[2][4];
  #pragma unroll
  for (int mt = 0; mt < 2; ++mt)
    #pragma unroll
    for (int nt = 0; nt < 4; ++nt)
      #pragma unroll
      for (int r = 0; r < 4; ++r) acc[mt][nt][r] = 0.f;

  int mw[2], mhh[2];
  #pragma unroll
  for (int mt = 0; mt < 2; ++mt) {
    int m = wm * 32 + mt * 16 + l15;
    mhh[mt] = m >> 5;
    mw[mt] = m & 31;
  }
  const size_t tokbase = ((size_t)b << 15) + ((size_t)d << 10) + ((size_t)h0 << 5);

  auto stage = [&](int dz) {
    const int zr = (d + dz + 31) & 31;
    #pragma unroll
    for (int p = 0; p < 8; ++p) {
      const int g = p * 256 + tid;
      const int tok = g >> 4, gi = g & 15;
      const int r = tok >> 5, w = tok & 31;
      const int yr = (h0 + r + 31) & 31;
      const size_t srcbyte = ((((size_t)b << 15) + ((size_t)zr << 10) + ((size_t)yr << 5) + w) << 8)
                             + (size_t)((gi ^ (w & 7)) << 4);
      gload_lds16((const char*)inT + srcbyte, (char*)Als + (size_t)g * 16);
    }
  };

  auto compute = [&](int dz) {
    #pragma unroll
    for (int dy = 0; dy < 3; ++dy) {
      const int tap = dz * 3 + dy;
      #pragma unroll
      for (int dx = 0; dx < 3; ++dx) {
        int abase[2], asw[2];
        #pragma unroll
        for (int mt = 0; mt < 2; ++mt) {
          const int wsft = (mw[mt] + dx + 31) & 31;
          const int stok = (mhh[mt] + dy) * 32 + wsft;
          abase[mt] = stok * 256;
          asw[mt] = (wsft & 7) << 4;
        }
        #pragma unroll
        for (int ks = 0; ks < 4; ++ks) {
          const int k2 = (ks * 32 + l4 * 8) * 2;
          const int bbase = (((tap * 3 + dx) * 4 + ks) * 4 + l4) * 1024;
          short8 afr[2], bfr[4];
          #pragma unroll
          for (int nt = 0; nt < 4; ++nt) {
            const int co = wn * 64 + nt * 16 + l15;
            bfr[nt] = *(const short8*)(Bp + bbase + co * 8);
          }
          #pragma unroll
          for (int mt = 0; mt < 2; ++mt)
            afr[mt] = *(const short8*)((const char*)Als + abase[mt] + (k2 ^ asw[mt]));
          #pragma unroll
          for (int mt = 0; mt < 2; ++mt)
            #pragma unroll
            for (int nt = 0; nt < 4; ++nt)
              acc[mt][nt] = __builtin_amdgcn_mfma_f32_16x16x32_bf16(afr[mt], bfr[nt],
                                                                    acc[mt][nt], 0, 0, 0);
        }
      }
    }
  };

  for (int dz = 0; dz < 3; ++dz) {
    stage(dz);
    __syncthreads();
    compute(dz);
    if (dz < 2) __syncthreads();
  }

  #pragma unroll
  for (int nt = 0; nt < 4; ++nt) {
    const int co = wn * 64 + nt * 16 + l15;
    const float bias = b1[co];
    float s = 0.f, q = 0.f;
    #pragma unroll
    for (int mt = 0; mt < 2; ++mt) {
      #pragma unroll
      for (int r = 0; r < 4; ++r) {
        const int m = wm * 32 + mt * 16 + l4 * 4 + r;
        const float v = acc[mt][nt][r] + bias;
        out[(tokbase + m) * 128 + co] = v;
        s += v; q += v * v;
      }
    }
    s += __shfl_xor(s, 16); s += __shfl_xor(s, 32);
    q += __shfl_xor(q, 16); q += __shfl_xor(q, 32);
    if (l4 == 0) { sumb[co][wm] = s; sqb[co][wm] = q; }
  }
  __syncthreads();
  if (tid < 128) {
    ps[blk * 128 + tid] = sumb[tid][0] + sumb[tid][1];
    pss[blk * 128 + tid] = sqb[tid][0] + sqb[tid][1];
  }
}

// ---------------------------------------------------------------------------
// K2: stats finalize, parallel
// ---------------------------------------------------------------------------
__global__ __launch_bounds__(64) void stats_final_kernel(
    const float* __restrict__ ps, const float* __restrict__ pss,
    float* __restrict__ mu, float* __restrict__ rs, int nb) {
  const int pair = blockIdx.x;  // b*128 + c
  const int b = pair >> 7, c = pair & 127;
  const int lane = threadIdx.x;
  float s = 0.f, ss = 0.f;
  for (int j = lane; j < nb; j += 64) {
    const int idx = ((b * nb + j) << 7) + c;
    s += ps[idx];
    ss += pss[idx];
  }
  #pragma unroll
  for (int o = 32; o > 0; o >>= 1) {
    s += __shfl_xor(s, o);
    ss += __shfl_xor(ss, o);
  }
  if (lane == 0) {
    float m = s * (1.0f / 32768.0f);
    float v = ss * (1.0f / 32768.0f) - m * m;
    mu[pair] = m;
    rs[pair] = rsqrtf(v + 1e-5f);
  }
}

// ---------------------------------------------------------------------------
// K3: 1x1 GEMM via bf16 MFMA, register-only (r7 proven).
// ---------------------------------------------------------------------------
template <int PRE, int AB16, int POST, int STATS>
__global__ __launch_bounds__(256) void gemm_mfma_kernel(
    const void* __restrict__ Avoid, const unsigned short* __restrict__ Wp,
    const float* __restrict__ bias, void* __restrict__ Yvoid, int O,
    const float* __restrict__ mu, const float* __restrict__ rs,
    const unsigned short* __restrict__ xtb, float* __restrict__ ps,
    float* __restrict__ pss) {
  __shared__ float sumb[128][2];
  __shared__ float sqb[128][2];
  const int tid = threadIdx.x;
  const int lane = tid & 63, wid = tid >> 6;
  const int wm = wid >> 1, wn = wid & 1;
  const int l15 = lane & 15, l4 = lane >> 4;
  const int og = blockIdx.x * 128;
  const int t0 = blockIdx.y * 128;
  const int bidx = t0 >> 15;
  const float* Af = (const float*)Avoid;
  const unsigned short* Ab = (const unsigned short*)Avoid;
  float* Yf = (float*)Yvoid;
  unsigned short* Yb = (unsigned short*)Yvoid;

  f32x4 acc[4][4];
  #pragma unroll
  for (int mt = 0; mt < 4; ++mt)
    #pragma unroll
    for (int nt = 0; nt < 4; ++nt)
      #pragma unroll
      for (int r = 0; r < 4; ++r) acc[mt][nt][r] = 0.f;

  #pragma unroll
  for (int ks = 0; ks < 4; ++ks) {
    const int kb = ks * 32 + l4 * 8;
    short8 a[4], bfr[4];
    float4 m0, m1, r0, r1;
    if constexpr (PRE == 1) {
      m0 = *(const float4*)(mu + bidx * 128 + kb);
      m1 = *(const float4*)(mu + bidx * 128 + kb + 4);
      r0 = *(const float4*)(rs + bidx * 128 + kb);
      r1 = *(const float4*)(rs + bidx * 128 + kb + 4);
    }
    #pragma unroll
    for (int mt = 0; mt < 4; ++mt) {
      const int tok = t0 + wm * 64 + mt * 16 + l15;
      float v[16];
      bool have = false;
      if constexpr (AB16 == 1) {
        if constexpr (PRE == 1) {
          bf16x16_load(Ab + (size_t)tok * 128 + kb, v);
          have = true;
        } else {
          a[mt] = *(const short8*)(Ab + (size_t)tok * 128 + kb);
        }
      } else {
        const float* ap = Af + (size_t)tok * 128 + kb;
        float4 v0 = *(const float4*)ap;
        float4 v1 = *(const float4*)(ap + 4);
        v[0] = v0.x; v[1] = v0.y; v[2] = v0.z; v[3] = v0.w;
        v[4] = v1.x; v[5] = v1.y; v[6] = v1.z; v[7] = v1.w;
        have = true;
      }
      if (have) {
        if constexpr (PRE == 1) {
          const float mm[8] = {m0.x, m0.y, m0.z, m0.w, m1.x, m1.y, m1.z, m1.w};
          const float rr[8] = {r0.x, r0.y, r0.z, r0.w, r1.x, r1.y, r1.z, r1.w};
          #pragma unroll
          for (int j = 0; j < 8; ++j) v[j] = gelu_f((v[j] - mm[j]) * rr[j]);
        }
        short8 t;
        #pragma unroll
        for (int j = 0; j < 8; ++j) t[j] = (short)f2bf(v[j]);
        a[mt] = t;
      }
    }
    #pragma unroll
    for (int nt = 0; nt < 4; ++nt) {
      const int o = og + wn * 64 + nt * 16 + l15;
      bfr[nt] = *(const short8*)(Wp + (size_t)o * 128 + kb);
    }
    #pragma unroll
    for (int mt = 0; mt < 4; ++mt)
      #pragma unroll
      for (int nt = 0; nt < 4; ++nt)
        acc[mt][nt] = __builtin_amdgcn_mfma_f32_16x16x32_bf16(a[mt], bfr[nt], acc[mt][nt], 0, 0, 0);
  }

  #pragma unroll
  for (int nt = 0; nt < 4; ++nt) {
    const int o = og + wn * 64 + nt * 16 + l15;
    const float bb = bias[o];
    float s = 0.f, q = 0.f;
    #pragma unroll
    for (int mt = 0; mt < 4; ++mt) {
      #pragma unroll
      for (int r = 0; r < 4; ++r) {
        const int t = t0 + wm * 64 + mt * 16 + l4 * 4 + r;
        const float v = acc[mt][nt][r] + bb;
        if constexpr (POST == 0) {
          Yf[(size_t)t * O + o] = v;
        } else if constexpr (POST == 1) {
          Yb[(size_t)t * 128 + o] = f2bf(sigmoid_f(v) * bf2f(xtb[(size_t)t * 128 + o]));
        } else if constexpr (POST == 2) {
          Yb[(size_t)t * O + o] = f2bf(v);
        } else {
          const int which = o >> 7, hsub = (o & 127) >> 4, ch = o & 15;
          Yb[((size_t)hsub * NTOK + t) * 48 + which * 16 + ch] = f2bf(v);
        }
        if constexpr (STATS) { s += v; q += v * v; }
      }
    }
    if constexpr (STATS) {
      s += __shfl_xor(s, 16); s += __shfl_xor(s, 32);
      q += __shfl_xor(q, 16); q += __shfl_xor(q, 32);
      if (l4 == 0) { sumb[o - og][wm] = s; sqb[o - og][wm] = q; }
    }
  }
  if constexpr (STATS) {
    __syncthreads();
    if (tid < 128) {
      ps[blockIdx.y * 128 + tid] = sumb[tid][0] + sumb[tid][1];
      pss[blockIdx.y * 128 + tid] = sqb[tid][0] + sqb[tid][1];
    }
  }
}

// ---------------------------------------------------------------------------
// K6: final projection over A0+A1+A2 (bf16), swapped orientation -> NCDHW
// ---------------------------------------------------------------------------
__global__ __launch_bounds__(256) void proj_mfma_kernel(
    const unsigned short* __restrict__ A0b, const unsigned short* __restrict__ A1b,
    const unsigned short* __restrict__ A2b, const unsigned short* __restrict__ Wp,
    const float* __restrict__ bias, float* __restrict__ out) {
  const int tid = threadIdx.x;
  const int lane = tid & 63, wid = tid >> 6;
  const int wm = wid >> 1, wn = wid & 1;
  const int l15 = lane & 15, l4 = lane >> 4;
  const int t0 = blockIdx.x * 128;

  f32x4 acc[4][4];
  #pragma unroll
  for (int mt = 0; mt < 4; ++mt)
    #pragma unroll
    for (int nt = 0; nt < 4; ++nt)
      #pragma unroll
      for (int r = 0; r < 4; ++r) acc[mt][nt][r] = 0.f;

  #pragma unroll
  for (int ks = 0; ks < 4; ++ks) {
    const int kb = ks * 32 + l4 * 8;
    short8 a[4], bfr[4];
    #pragma unroll
    for (int mt = 0; mt < 4; ++mt) {
      const int o = wm * 64 + mt * 16 + l15;
      a[mt] = *(const short8*)(Wp + (size_t)o * 128 + kb);
    }
    #pragma unroll
    for (int nt = 0; nt < 4; ++nt) {
      const int tok = t0 + wn * 64 + nt * 16 + l15;
      const size_t off = (size_t)tok * 128 + kb;
      short8 s0 = *(const short8*)(A0b + off);
      short8 s1 = *(const short8*)(A1b + off);
      short8 s2 = *(const short8*)(A2b + off);
      short8 r;
      #pragma unroll
      for (int i = 0; i < 8; ++i) {
        float f = bf2f((unsigned short)s0[i]) + bf2f((unsigned short)s1[i]) +
                  bf2f((unsigned short)s2[i]);
        r[i] = (short)f2bf(f);
      }
      bfr[nt] = r;
    }
    #pragma unroll
    for (int mt = 0; mt < 4; ++mt)
      #pragma unroll
      for (int nt = 0; nt < 4; ++nt)
        acc[mt][nt] = __builtin_amdgcn_mfma_f32_16x16x32_bf16(a[mt], bfr[nt], acc[mt][nt], 0, 0, 0);
  }

  #pragma unroll
  for (int nt = 0; nt < 4; ++nt) {
    const int tok = t0 + wn * 64 + nt * 16 + l15;
    const int dhw = tok & 32767, bB = tok >> 15;
    #pragma unroll
    for (int mt = 0; mt < 4; ++mt) {
      #pragma unroll
      for (int r = 0; r < 4; ++r) {
        const int o = wm * 64 + mt * 16 + l4 * 4 + r;
        out[((size_t)(bB * 128 + o) << 15) + dhw] = acc[mt][nt][r] + bias[o];
      }
    }
  }
}

// ---------------------------------------------------------------------------
// K7: axial attention via MFMA. One wave per (seq, head, axial).
// Algebra: q_r.k_r == q.k with ch15 of q,k scaled by |Rqk00| (3x3 blocks are
// orthonormal; only the padded ch15 block survives). V-rotation is postponed
// to the 32 outputs (linearity). Effective logit adds -lin[k]*pbw[comp].
// S^T = mfma_32x32x16(K,Q): lane holds 16 scores of query q=lane&31
// (k = (r&3)+4*hi+8*(r>>2)); softmax is in-lane + one shfl_xor(32).
// P->bf16 A-frags via cvt_pk + shfl_xor half-exchange; V^T staged in LDS as
// the B operand; PV = 2 mfma (K split 16+16, cols 16-31 unused).
// ---------------------------------------------------------------------------
__global__ __launch_bounds__(64) void attn_mfma_kernel(
    const unsigned short* __restrict__ qkvh, const float* __restrict__ Rbuf,
    const float* __restrict__ pbw, unsigned short* __restrict__ a0,
    unsigned short* __restrict__ a1, unsigned short* __restrict__ a2) {
  __shared__ unsigned short Vt[16 * 40];  // [d][tok], row pad 40 shorts
  __shared__ float Ot[32 * 20];           // [tok][d], row pad 20 floats
  const int axial = blockIdx.z;
  const int head = blockIdx.y;
  const int seq = blockIdx.x;
  unsigned short* dstbuf = (axial == 0) ? a0 : ((axial == 1) ? a1 : a2);
  const int lane = threadIdx.x;
  const int tok = lane & 31, hi = lane >> 5;
  const int b = seq >> 10, rem = seq & 1023;
  const int u = rem >> 5, v = rem & 31;
  int base, stride, comp;
  if (axial == 0)      { base = (b << 15) + (u << 5) + v;         stride = 1024; comp = 2; }
  else if (axial == 1) { base = (b << 15) + (u << 10) + v;        stride = 32;   comp = 1; }
  else                 { base = (b << 15) + (u << 10) + (v << 5); stride = 1;    comp = 0; }
  const float* Rp = Rbuf + (axial * 8 + head) * 18;
  const float rq00 = fabsf(Rp[0]);
  const size_t t_tok = (size_t)base + (size_t)tok * stride;
  const unsigned short* row = qkvh + (size_t)head * ((size_t)NTOK * 48) + t_tok * 48;
  short8 aq = *(const short8*)(row + hi * 8);
  short8 ak = *(const short8*)(row + 16 + hi * 8);
  short8 av = *(const short8*)(row + 32 + hi * 8);
  if (hi) {  // ch15 carries the R00^2 correction
    aq[7] = (short)f2bf(bf2f((unsigned short)aq[7]) * rq00);
    ak[7] = (short)f2bf(bf2f((unsigned short)ak[7]) * rq00);
  }
  // stage V^T: Vt[d][tok]
  #pragma unroll
  for (int e = 0; e < 8; ++e) Vt[(hi * 8 + e) * 40 + tok] = (unsigned short)av[e];
  __syncthreads();
  // S^T = K·Q^T
  f32x16 sacc;
  #pragma unroll
  for (int r = 0; r < 16; ++r) sacc[r] = 0.f;
  sacc = __builtin_amdgcn_mfma_f32_32x32x16_bf16(ak, aq, sacc, 0, 0, 0);
  const float wb = pbw[comp];
  float p[16];
  float mmax = -1e30f;
  #pragma unroll
  for (int r = 0; r < 16; ++r) {
    const int kk = (r & 3) + 4 * hi + 8 * (r >> 2);
    const float lin = -1.0f + (2.0f / 31.0f) * (float)kk;
    p[r] = sacc[r] * 0.25f - lin * wb;
    mmax = fmaxf(mmax, p[r]);
  }
  mmax = fmaxf(mmax, __shfl_xor(mmax, 32));
  float sum = 0.f;
  #pragma unroll
  for (int r = 0; r < 16; ++r) { p[r] = expf(p[r] - mmax); sum += p[r]; }
  sum += __shfl_xor(sum, 32);
  const float inv = 1.0f / sum;
  #pragma unroll
  for (int r = 0; r < 16; ++r) p[r] *= inv;
  // pack to bf16 pairs and redistribute halves across the hi boundary
  unsigned pk[8], sw[8];
  #pragma unroll
  for (int j = 0; j < 8; ++j) {
    unsigned r_;
    asm("v_cvt_pk_bf16_f32 %0, %1, %2" : "=v"(r_) : "v"(p[2 * j]), "v"(p[2 * j + 1]));
    pk[j] = r_;
  }
  #pragma unroll
  for (int j = 0; j < 8; ++j) sw[j] = (unsigned)__shfl_xor((int)pk[j], 32);
  uint4 Fu, Gu;
  Fu.x = hi ? sw[2] : pk[0];
  Fu.y = hi ? sw[3] : pk[1];
  Fu.z = hi ? pk[2] : sw[0];
  Fu.w = hi ? pk[3] : sw[1];
  Gu.x = hi ? sw[6] : pk[4];
  Gu.y = hi ? sw[7] : pk[5];
  Gu.z = hi ? pk[6] : sw[4];
  Gu.w = hi ? pk[7] : sw[5];
  short8 Pf = *(short8*)&Fu;
  short8 Pg = *(short8*)&Gu;
  // B operand: V^T columns (lanes 16-31 duplicate 0-15; D cols 16-31 unused)
  const unsigned short* vrow = Vt + (tok & 15) * 40;
  short8 Bv0 = *(const short8*)(vrow + hi * 8);
  short8 Bv1 = *(const short8*)(vrow + 16 + hi * 8);
  f32x16 oacc;
  #pragma unroll
  for (int r = 0; r < 16; ++r) oacc[r] = 0.f;
  oacc = __builtin_amdgcn_mfma_f32_32x32x16_bf16(Pf, Bv0, oacc, 0, 0, 0);
  oacc = __builtin_amdgcn_mfma_f32_32x32x16_bf16(Pg, Bv1, oacc, 0, 0, 0);
  // D: col=d=lane&31 (<16 valid), row q=(r&3)+4*hi+8*(r>>2)
  if (tok < 16) {
    #pragma unroll
    for (int r = 0; r < 16; ++r) {
      const int q = (r & 3) + 4 * hi + 8 * (r >> 2);
      Ot[q * 20 + tok] = oacc[r];
    }
  }
  __syncthreads();
  // output rotation (R_v, postponed) + bf16 store, one token per lane<32
  if (lane < 32) {
    float o16[16], y16[16], Rv[9];
    #pragma unroll
    for (int j = 0; j < 16; ++j) o16[j] = Ot[lane * 20 + j];
    #pragma unroll
    for (int i = 0; i < 9; ++i) Rv[i] = Rp[9 + i];
    rot16(Rv, o16, y16);
    unsigned outw[8];
    #pragma unroll
    for (int j = 0; j < 8; ++j)
      outw[j] = ((unsigned)f2bf(y16[2 * j + 1]) << 16) | (unsigned)f2bf(y16[2 * j]);
    const size_t t2 = (size_t)base + (size_t)lane * stride;
    unsigned short* dst = dstbuf + t2 * 128 + head * 16;
    uint4 o0 = {outw[0], outw[1], outw[2], outw[3]};
    uint4 o1 = {outw[4], outw[5], outw[6], outw[7]};
    *(uint4*)dst = o0;
    *(uint4*)(dst + 8) = o1;
  }
}

// ---------------------------------------------------------------------------
extern "C" void kernel_launch(void* const* d_in, const int* in_sizes, int n_in,
                              void* d_out, int out_size, void* d_ws, size_t ws_size,
                              hipStream_t stream) {
  const float* x       = (const float*)d_in[0];
  const float* pos_emb = (const float*)d_in[1];
  const float* qkv_w   = (const float*)d_in[2];
  const float* qkv_b   = (const float*)d_in[3];
  const float* lp_w1   = (const float*)d_in[4];
  const float* lp_b1   = (const float*)d_in[5];
  const float* lp_w2   = (const float*)d_in[6];
  const float* lp_b2   = (const float*)d_in[7];
  const float* mod_w1  = (const float*)d_in[8];
  const float* mod_b1  = (const float*)d_in[9];
  const float* mod_w2  = (const float*)d_in[10];
  const float* mod_b2  = (const float*)d_in[11];
  // d_in[12] pa_w, d_in[13] pa_b: cancel in softmax (constant along key axis)
  const float* proj_w  = (const float*)d_in[14];
  const float* proj_b  = (const float*)d_in[15];
  const float* pbw     = (const float*)d_in[16];
  // d_in[17] pos_bias_b: cancels in softmax
  const float* Ad      = (const float*)d_in[18];
  const float* Ah      = (const float*)d_in[19];
  const float* Aw      = (const float*)d_in[20];
  const float* Rd      = (const float*)d_in[21];
  const float* Rh      = (const float*)d_in[22];
  const float* Rw      = (const float*)d_in[23];
  // d_in[24..26] t_d/t_h/t_w: cancel in rel (pairwise difference)

  float* ws = (float*)d_ws;
  float* R0     = ws + WS_R0;
  unsigned short* A0b    = (unsigned short*)(ws + WS_A0);
  unsigned short* A1b    = (unsigned short*)(ws + WS_A1);
  unsigned short* A2b    = (unsigned short*)(ws + WS_A2);
  unsigned short* mpreb  = (unsigned short*)(ws + WS_MPREB);
  unsigned short* xtokb  = (unsigned short*)(ws + WS_XTOKB);
  unsigned short* inT    = (unsigned short*)(ws + WS_INT);
  unsigned short* qkvh   = (unsigned short*)(ws + WS_QKVH);
  unsigned short* convP  = (unsigned short*)(ws + WS_CONVP);
  unsigned short* qkvP   = (unsigned short*)(ws + WS_QKVP);
  unsigned short* WcP    = (unsigned short*)(ws + WS_WCP);
  unsigned short* modw2P = (unsigned short*)(ws + WS_MODW2P);
  unsigned short* projP  = (unsigned short*)(ws + WS_PROJP);
  float* bc     = ws + WS_BC;
  float* Rbuf   = ws + WS_RBUF;
  float* ps     = ws + WS_PS;
  float* pss    = ws + WS_PSS;
  float* mu1    = ws + WS_MU1;
  float* rs1    = ws + WS_RS1;
  float* mu2    = ws + WS_MU2;
  float* rs2    = ws + WS_RS2;
  unsigned short* xmodb = inT;  // x_mod bf16 reuses INT region (inT dead after conv)

  prep_w_kernel<<<256, 256, 0, stream>>>(lp_w1, qkv_w, mod_w1, lp_w2, lp_b2, mod_b1,
                                         mod_w2, proj_w, Ad, Ah, Aw, Rd, Rh, Rw,
                                         convP, qkvP, WcP, modw2P, projP, bc, Rbuf);
  transpose_kernel<<<2048, 256, 0, stream>>>(x, pos_emb, xtokb, inT);
  conv_mfma_kernel<<<1024, 256, 0, stream>>>(inT, convP, lp_b1, R0, ps, pss);
  stats_final_kernel<<<256, 64, 0, stream>>>(ps, pss, mu1, rs1, 512);
  gemm_mfma_kernel<1, 0, 2, 1><<<dim3(1, 512), 256, 0, stream>>>(
      R0, WcP, bc, mpreb, 128, mu1, rs1, nullptr, ps, pss);
  stats_final_kernel<<<256, 64, 0, stream>>>(ps, pss, mu2, rs2, 256);
  gemm_mfma_kernel<1, 1, 1, 0><<<dim3(1, 512), 256, 0, stream>>>(
      mpreb, modw2P, mod_b2, xmodb, 128, mu2, rs2, xtokb, nullptr, nullptr);
  gemm_mfma_kernel<0, 1, 3, 0><<<dim3(3, 512), 256, 0, stream>>>(
      xmodb, qkvP, qkv_b, qkvh, 384, nullptr, nullptr, nullptr, nullptr, nullptr);
  // MFMA attention: one wave per (seq, head, axial)
  attn_mfma_kernel<<<dim3(2048, 8, 3), 64, 0, stream>>>(qkvh, Rbuf, pbw, A0b, A1b, A2b);
  proj_mfma_kernel<<<512, 256, 0, stream>>>(A0b, A1b, A2b, projP, proj_b, (float*)d_out);
}